// Round 1
// baseline (621.828 us; speedup 1.0000x reference)
//
#include <hip/hip_runtime.h>
#include <hip/hip_bf16.h>

// ---------------------------------------------------------------------------
// FlashSVDBlockDA: low-rank transformer block on MI355X (gfx950)
// B=8 M=1024 DM=768 H=12 DH=64 R=32 RFF=384 DFF=3072 RWO=384
// Strategy: fold low-rank weight pairs once per launch (cheap), run all big
// matmuls as bf16 MFMA (16x16x32) GEMMs with K-contiguous operands, flash
// attention with online softmax, fp32 LN.
// ---------------------------------------------------------------------------

typedef float f32x4 __attribute__((ext_vector_type(4)));
typedef __bf16 bf16x8 __attribute__((ext_vector_type(8)));

#define NB   8
#define NM   1024
#define NDM  768
#define NH   12
#define NDH  64
#define NR   32
#define NRFF 384
#define NDFF 3072
#define NRWO 384
#define ROWS (NB*NM)   // 8192
#define NQKV 2304      // 3*H*DH

// ---------------------------------------------------------------- small preps

__global__ void castb_kernel(const float* __restrict__ s, __hip_bfloat16* __restrict__ d, int n) {
  for (int i = blockIdx.x * blockDim.x + threadIdx.x; i < n; i += gridDim.x * blockDim.x)
    d[i] = __float2bfloat16(s[i]);
}

// dst[C][R] = cast(src[R][C])^T
__global__ void tcast_kernel(const float* __restrict__ src, __hip_bfloat16* __restrict__ dst, int R, int C) {
  int total = R * C;
  for (int i = blockIdx.x * blockDim.x + threadIdx.x; i < total; i += gridDim.x * blockDim.x) {
    int c = i / R, r = i - c * R;
    dst[i] = __float2bfloat16(src[(size_t)r * C + c]);
  }
}

// WqkvT[n][dm], n = t*768 + h*64 + dh ; W_t[h] = P_t[h] @ V_t[h]; also bqkv[n]
__global__ __launch_bounds__(256) void prep_wqkvT(
    const float* __restrict__ Pq, const float* __restrict__ Vq, const float* __restrict__ bq,
    const float* __restrict__ Pk, const float* __restrict__ Vk, const float* __restrict__ bk,
    const float* __restrict__ Pv, const float* __restrict__ Vv, const float* __restrict__ bv,
    __hip_bfloat16* __restrict__ wT, float* __restrict__ bqkv) {
  int n = blockIdx.x;
  int t = n / NDM, rem = n % NDM, h = rem >> 6, dh = rem & 63;
  const float* P = (t == 0) ? Pq : (t == 1) ? Pk : Pv;
  const float* V = (t == 0) ? Vq : (t == 1) ? Vk : Vv;
  const float* bb = (t == 0) ? bq : (t == 1) ? bk : bv;
  __shared__ float vcol[NR];
  if (threadIdx.x < NR) vcol[threadIdx.x] = V[((size_t)h * NR + threadIdx.x) * NDH + dh];
  __syncthreads();
  for (int dm = threadIdx.x; dm < NDM; dm += 256) {
    const float* pp = P + ((size_t)h * NDM + dm) * NR;
    float s = 0.f;
#pragma unroll
    for (int r = 0; r < NR; r++) s += pp[r] * vcol[r];
    wT[(size_t)n * NDM + dm] = __float2bfloat16(s);
  }
  if (threadIdx.x == 0) bqkv[n] = bb[h * NDH + dh];
}

// WoT[n][k] = sum_r Uo[k][r] * Vo[r][n]
__global__ __launch_bounds__(256) void prep_woT(const float* __restrict__ Uo, const float* __restrict__ Vo,
                                                __hip_bfloat16* __restrict__ wT) {
  int n = blockIdx.x;
  __shared__ float vc[NRWO];
  for (int r = threadIdx.x; r < NRWO; r += 256) vc[r] = Vo[(size_t)r * NDM + n];
  __syncthreads();
  for (int k = threadIdx.x; k < NDM; k += 256) {
    const float* u = Uo + (size_t)k * NRWO;
    float s = 0.f;
#pragma unroll 8
    for (int r = 0; r < NRWO; r++) s += u[r] * vc[r];
    wT[(size_t)n * NDM + k] = __float2bfloat16(s);
  }
}

// ---------------------------------------------------------------- GEMM (bf16)
// C[M][N] = A[M][K] @ Bt[N][K]^T, 128x128 tile, BK=64, 4 waves (2x2), each wave
// 64x64 out = 4x4 frags of 16x16x32 MFMA. LDS XOR-swizzled ((row&7)<<4 on byte).
// EPI: 0 = ->bf16 ; 1 = +bias ->bf16 ; 2 = gelu(+bias) ->bf16 ; 3 = +bias+resid ->f32
template <int EPI>
__global__ __launch_bounds__(256) void gemm_bt(
    const __hip_bfloat16* __restrict__ A, const __hip_bfloat16* __restrict__ Bt,
    int M, int N, int K,
    const float* __restrict__ bias, const float* __restrict__ resid,
    __hip_bfloat16* __restrict__ outb, float* __restrict__ outf) {
  __shared__ __align__(16) char lsA[128 * 128];
  __shared__ __align__(16) char lsB[128 * 128];
  const int tid = threadIdx.x;
  const int lane = tid & 63, wid = tid >> 6;
  const int wr = wid >> 1, wc = wid & 1;
  const int bm = blockIdx.y * 128, bn = blockIdx.x * 128;
  const int g = lane >> 4, q = lane & 15;

  f32x4 acc[4][4];
#pragma unroll
  for (int i = 0; i < 4; i++)
#pragma unroll
    for (int j = 0; j < 4; j++) acc[i][j] = f32x4{0.f, 0.f, 0.f, 0.f};

  for (int k0 = 0; k0 < K; k0 += 64) {
#pragma unroll
    for (int c = 0; c < 4; c++) {
      int idx = tid + c * 256;
      int row = idx >> 3, kc = idx & 7;
      uint4 va = *(const uint4*)(A + (size_t)(bm + row) * K + k0 + kc * 8);
      *(uint4*)&lsA[row * 128 + ((kc * 16) ^ ((row & 7) << 4))] = va;
      uint4 vb = *(const uint4*)(Bt + (size_t)(bn + row) * K + k0 + kc * 8);
      *(uint4*)&lsB[row * 128 + ((kc * 16) ^ ((row & 7) << 4))] = vb;
    }
    __syncthreads();
#pragma unroll
    for (int ks = 0; ks < 2; ks++) {
      bf16x8 af[4], bfr[4];
#pragma unroll
      for (int i = 0; i < 4; i++) {
        int ra = wr * 64 + i * 16 + q;
        af[i] = *(const bf16x8*)&lsA[ra * 128 + ((ks * 64 + g * 16) ^ ((ra & 7) << 4))];
        int rb = wc * 64 + i * 16 + q;
        bfr[i] = *(const bf16x8*)&lsB[rb * 128 + ((ks * 64 + g * 16) ^ ((rb & 7) << 4))];
      }
#pragma unroll
      for (int i = 0; i < 4; i++)
#pragma unroll
        for (int j = 0; j < 4; j++)
          acc[i][j] = __builtin_amdgcn_mfma_f32_16x16x32_bf16(af[i], bfr[j], acc[i][j], 0, 0, 0);
    }
    __syncthreads();
  }

#pragma unroll
  for (int i = 0; i < 4; i++)
#pragma unroll
    for (int j = 0; j < 4; j++)
#pragma unroll
      for (int e = 0; e < 4; e++) {
        int row = bm + wr * 64 + i * 16 + g * 4 + e;
        int col = bn + wc * 64 + j * 16 + q;
        float v = acc[i][j][e];
        if (EPI == 1 || EPI == 2 || EPI == 3) v += bias[col];
        if (EPI == 2) v = 0.5f * v * (1.0f + erff(v * 0.70710678118654752f));
        if (EPI == 3) {
          v += resid[(size_t)row * N + col];
          outf[(size_t)row * N + col] = v;
        } else {
          outb[(size_t)row * N + col] = __float2bfloat16(v);
        }
      }
}

// ------------------------------------------------------------- flash attention
// qkv[8192][2304] layout: cols t*768 + h*64 + dh. Per block: one (b,h,64-row
// Q tile); 4 waves x 16 rows. KV tiles of 64 staged in LDS (K swizzled
// row-major, V transposed + swizzled). Online softmax in fp32.
__global__ __launch_bounds__(256) void attn_kernel(const __hip_bfloat16* __restrict__ qkv,
                                                   const float* __restrict__ mask,
                                                   __hip_bfloat16* __restrict__ attnb) {
  __shared__ __align__(16) char Kl[64 * 128];
  __shared__ __align__(16) char Vl[64 * 128];   // transposed: [dh][n]
  __shared__ __align__(16) char Pl[4][16 * 128];
  const int blk = blockIdx.x;
  const int qb = blk & 15;
  const int h = (blk >> 4) % NH;
  const int b = blk / (16 * NH);
  const int tid = threadIdx.x;
  const int lane = tid & 63, w = tid >> 6;
  const int g = lane >> 4, q = lane & 15;
  const size_t rowbase = (size_t)b * NM;

  bf16x8 qf[2];
#pragma unroll
  for (int ks = 0; ks < 2; ks++)
    qf[ks] = *(const bf16x8*)(qkv + (rowbase + qb * 64 + w * 16 + q) * NQKV + h * 64 + g * 8 + ks * 32);

  f32x4 oacc[4];
#pragma unroll
  for (int dt = 0; dt < 4; dt++) oacc[dt] = f32x4{0.f, 0.f, 0.f, 0.f};
  float mrun[4] = {-1e30f, -1e30f, -1e30f, -1e30f};
  float lrun[4] = {0.f, 0.f, 0.f, 0.f};

  for (int t = 0; t < NM / 64; t++) {
    const int kv0 = t * 64;
    // stage K
#pragma unroll
    for (int i = 0; i < 2; i++) {
      int idx = tid + i * 256;
      int row = idx >> 3, kc = idx & 7;
      uint4 v = *(const uint4*)(qkv + (rowbase + kv0 + row) * NQKV + NDM + h * 64 + kc * 8);
      *(uint4*)&Kl[row * 128 + ((kc * 16) ^ ((row & 7) << 4))] = v;
    }
    // stage V transposed
#pragma unroll
    for (int i = 0; i < 2; i++) {
      int n = tid & 63;
      int dh0 = (tid >> 6) * 8 + i * 32;
      uint4 v = *(const uint4*)(qkv + (rowbase + kv0 + n) * NQKV + 2 * NDM + h * 64 + dh0);
      unsigned short us[8];
      *(uint4*)us = v;
#pragma unroll
      for (int j = 0; j < 8; j++) {
        int dh = dh0 + j;
        *(unsigned short*)&Vl[dh * 128 + ((n * 2) ^ ((dh & 7) << 4))] = us[j];
      }
    }
    __syncthreads();

    // S = Q K^T
    f32x4 sacc[4];
#pragma unroll
    for (int nt = 0; nt < 4; nt++) sacc[nt] = f32x4{0.f, 0.f, 0.f, 0.f};
#pragma unroll
    for (int ks = 0; ks < 2; ks++) {
#pragma unroll
      for (int nt = 0; nt < 4; nt++) {
        int r = nt * 16 + q;
        bf16x8 kf = *(const bf16x8*)&Kl[r * 128 + ((ks * 64 + g * 16) ^ ((r & 7) << 4))];
        sacc[nt] = __builtin_amdgcn_mfma_f32_16x16x32_bf16(qf[ks], kf, sacc[nt], 0, 0, 0);
      }
    }

    // scale + mask; online softmax (row r = 4*g + e lives in 16-lane group g)
    float mk[4];
#pragma unroll
    for (int nt = 0; nt < 4; nt++) mk[nt] = mask[b * NM + kv0 + nt * 16 + q];
    float pv[4][4];
    float mx[4];
#pragma unroll
    for (int e = 0; e < 4; e++) {
      float m0 = -1e30f;
#pragma unroll
      for (int nt = 0; nt < 4; nt++) {
        float s = sacc[nt][e] * 0.125f + mk[nt];
        pv[nt][e] = s;
        m0 = fmaxf(m0, s);
      }
      mx[e] = m0;
    }
#pragma unroll
    for (int d = 1; d < 16; d <<= 1)
#pragma unroll
      for (int e = 0; e < 4; e++) mx[e] = fmaxf(mx[e], __shfl_xor(mx[e], d));
    float corr[4], rs[4];
#pragma unroll
    for (int e = 0; e < 4; e++) {
      float mn = fmaxf(mrun[e], mx[e]);
      corr[e] = __expf(mrun[e] - mn);
      mrun[e] = mn;
    }
#pragma unroll
    for (int e = 0; e < 4; e++) {
      float s = 0.f;
#pragma unroll
      for (int nt = 0; nt < 4; nt++) {
        float p = __expf(pv[nt][e] - mrun[e]);
        pv[nt][e] = p;
        s += p;
      }
      rs[e] = s;
    }
#pragma unroll
    for (int d = 1; d < 16; d <<= 1)
#pragma unroll
      for (int e = 0; e < 4; e++) rs[e] += __shfl_xor(rs[e], d);
#pragma unroll
    for (int e = 0; e < 4; e++) lrun[e] = lrun[e] * corr[e] + rs[e];
#pragma unroll
    for (int dt = 0; dt < 4; dt++)
#pragma unroll
      for (int e = 0; e < 4; e++) oacc[dt][e] *= corr[e];

    // write P (D-layout -> A-layout via per-wave LDS)
#pragma unroll
    for (int nt = 0; nt < 4; nt++)
#pragma unroll
      for (int e = 0; e < 4; e++) {
        int r = g * 4 + e;
        int colb = (nt * 16 + q) * 2;
        *(__hip_bfloat16*)&Pl[w][r * 128 + (colb ^ ((r & 7) << 4))] = __float2bfloat16(pv[nt][e]);
      }

    // O += P @ V
#pragma unroll
    for (int ks = 0; ks < 2; ks++) {
      bf16x8 pf = *(const bf16x8*)&Pl[w][q * 128 + ((ks * 64 + g * 16) ^ ((q & 7) << 4))];
#pragma unroll
      for (int dt = 0; dt < 4; dt++) {
        int r = dt * 16 + q;
        bf16x8 vf = *(const bf16x8*)&Vl[r * 128 + ((ks * 64 + g * 16) ^ ((r & 7) << 4))];
        oacc[dt] = __builtin_amdgcn_mfma_f32_16x16x32_bf16(pf, vf, oacc[dt], 0, 0, 0);
      }
    }
    __syncthreads();
  }

  // final normalize + store [b,m, h*64+dh]
#pragma unroll
  for (int dt = 0; dt < 4; dt++)
#pragma unroll
    for (int e = 0; e < 4; e++) {
      int r = g * 4 + e;
      int m = qb * 64 + w * 16 + r;
      int dh = dt * 16 + q;
      attnb[(rowbase + m) * NDM + h * 64 + dh] = __float2bfloat16(oacc[dt][e] / lrun[e]);
    }
}

// ------------------------------------------------------------------- layernorm
__global__ __launch_bounds__(256) void ln_kernel(const float* __restrict__ in, const float* __restrict__ gam,
                                                 const float* __restrict__ bet, float* __restrict__ outf,
                                                 __hip_bfloat16* __restrict__ outb) {
  const int row = blockIdx.x, tid = threadIdx.x;
  const float* p = in + (size_t)row * NDM;
  float v0 = p[tid], v1 = p[tid + 256], v2 = p[tid + 512];
  float s = v0 + v1 + v2, s2 = v0 * v0 + v1 * v1 + v2 * v2;
#pragma unroll
  for (int d = 1; d < 64; d <<= 1) {
    s += __shfl_xor(s, d);
    s2 += __shfl_xor(s2, d);
  }
  __shared__ float red[8];
  int w = tid >> 6;
  if ((tid & 63) == 0) { red[w] = s; red[4 + w] = s2; }
  __syncthreads();
  s = red[0] + red[1] + red[2] + red[3];
  s2 = red[4] + red[5] + red[6] + red[7];
  float mu = s * (1.0f / NDM);
  float var = fmaxf(s2 * (1.0f / NDM) - mu * mu, 0.0f);
  float rr = rsqrtf(var + 1e-12f);
  float o0 = (v0 - mu) * rr * gam[tid] + bet[tid];
  float o1 = (v1 - mu) * rr * gam[tid + 256] + bet[tid + 256];
  float o2 = (v2 - mu) * rr * gam[tid + 512] + bet[tid + 512];
  float* po = outf + (size_t)row * NDM;
  po[tid] = o0;
  po[tid + 256] = o1;
  po[tid + 512] = o2;
  if (outb) {
    __hip_bfloat16* pb = outb + (size_t)row * NDM;
    pb[tid] = __float2bfloat16(o0);
    pb[tid + 256] = __float2bfloat16(o1);
    pb[tid + 512] = __float2bfloat16(o2);
  }
}

// ------------------------------------------------------------------- launcher
extern "C" void kernel_launch(void* const* d_in, const int* in_sizes, int n_in,
                              void* d_out, int out_size, void* d_ws, size_t ws_size,
                              hipStream_t stream) {
  const float* x = (const float*)d_in[0];
  const float* mask = (const float*)d_in[1];
  const float* Pq = (const float*)d_in[2];
  const float* Vq = (const float*)d_in[3];
  const float* bq = (const float*)d_in[4];
  const float* Pk = (const float*)d_in[5];
  const float* Vk = (const float*)d_in[6];
  const float* bk = (const float*)d_in[7];
  const float* Pv = (const float*)d_in[8];
  const float* Vv = (const float*)d_in[9];
  const float* bv = (const float*)d_in[10];
  const float* Uo = (const float*)d_in[11];
  const float* Vo = (const float*)d_in[12];
  const float* bo = (const float*)d_in[13];
  const float* U1 = (const float*)d_in[14];
  const float* V1 = (const float*)d_in[15];
  const float* b1 = (const float*)d_in[16];
  const float* U2 = (const float*)d_in[17];
  const float* V2 = (const float*)d_in[18];
  const float* b2 = (const float*)d_in[19];
  const float* ln1g = (const float*)d_in[20];
  const float* ln1b = (const float*)d_in[21];
  const float* ln2g = (const float*)d_in[22];
  const float* ln2b = (const float*)d_in[23];
  float* out = (float*)d_out;
  char* ws = (char*)d_ws;

  size_t off = 0;
  auto alloc = [&](size_t bytes) { size_t o = off; off += (bytes + 255) & ~(size_t)255; return o; };
  const size_t o_xb    = alloc((size_t)ROWS * NDM * 2);
  const size_t o_wqkvT = alloc((size_t)NQKV * NDM * 2);
  const size_t o_bqkv  = alloc((size_t)NQKV * 4);
  const size_t o_woT   = alloc((size_t)NDM * NDM * 2);
  const size_t o_u1T   = alloc((size_t)NRFF * NDM * 2);
  const size_t o_v1T   = alloc((size_t)NDFF * NRFF * 2);
  const size_t o_u2T   = alloc((size_t)NRFF * NDFF * 2);
  const size_t o_v2T   = alloc((size_t)NDM * NRFF * 2);
  const size_t o_qkv   = alloc((size_t)ROWS * NQKV * 2);   // 37.75 MB
  const size_t o_attnb = alloc((size_t)ROWS * NDM * 2);    // contiguous after qkv
  const size_t o_tmp   = alloc((size_t)ROWS * NDM * 4);    // pre-LN buffer (reused)
  const size_t o_x1f   = alloc((size_t)ROWS * NDM * 4);
  const size_t o_x1b   = alloc((size_t)ROWS * NDM * 2);
  const size_t o_mid   = alloc((size_t)ROWS * NRFF * 2);
  const size_t o_mid2  = alloc((size_t)ROWS * NRFF * 2);
  const size_t o_hdn   = o_qkv;  // hdn [8192][3072] bf16 reuses qkv+attnb (both dead)

  __hip_bfloat16* xb    = (__hip_bfloat16*)(ws + o_xb);
  __hip_bfloat16* wqkvT = (__hip_bfloat16*)(ws + o_wqkvT);
  float*          bqkv  = (float*)(ws + o_bqkv);
  __hip_bfloat16* woT   = (__hip_bfloat16*)(ws + o_woT);
  __hip_bfloat16* u1T   = (__hip_bfloat16*)(ws + o_u1T);
  __hip_bfloat16* v1T   = (__hip_bfloat16*)(ws + o_v1T);
  __hip_bfloat16* u2T   = (__hip_bfloat16*)(ws + o_u2T);
  __hip_bfloat16* v2T   = (__hip_bfloat16*)(ws + o_v2T);
  __hip_bfloat16* qkv   = (__hip_bfloat16*)(ws + o_qkv);
  __hip_bfloat16* attnb = (__hip_bfloat16*)(ws + o_attnb);
  float*          tmp   = (float*)(ws + o_tmp);
  float*          x1f   = (float*)(ws + o_x1f);
  __hip_bfloat16* x1b   = (__hip_bfloat16*)(ws + o_x1b);
  __hip_bfloat16* mid   = (__hip_bfloat16*)(ws + o_mid);
  __hip_bfloat16* mid2  = (__hip_bfloat16*)(ws + o_mid2);
  __hip_bfloat16* hdn   = (__hip_bfloat16*)(ws + o_hdn);

  // --- prep
  castb_kernel<<<1024, 256, 0, stream>>>(x, xb, ROWS * NDM);
  prep_wqkvT<<<NQKV, 256, 0, stream>>>(Pq, Vq, bq, Pk, Vk, bk, Pv, Vv, bv, wqkvT, bqkv);
  prep_woT<<<NDM, 256, 0, stream>>>(Uo, Vo, woT);
  tcast_kernel<<<1024, 256, 0, stream>>>(U1, u1T, NDM, NRFF);
  tcast_kernel<<<1024, 256, 0, stream>>>(V1, v1T, NRFF, NDFF);
  tcast_kernel<<<1024, 256, 0, stream>>>(U2, u2T, NDFF, NRFF);
  tcast_kernel<<<1024, 256, 0, stream>>>(V2, v2T, NRFF, NDM);

  // --- QKV = xb @ WqkvT^T + bqkv
  gemm_bt<1><<<dim3(NQKV / 128, ROWS / 128), 256, 0, stream>>>(xb, wqkvT, ROWS, NQKV, NDM, bqkv, nullptr, qkv, nullptr);

  // --- attention
  attn_kernel<<<NB * NH * (NM / 64), 256, 0, stream>>>(qkv, mask, attnb);

  // --- Wo proj + bias + residual(x) -> tmp(f32); LN1 -> x1f, x1b
  gemm_bt<3><<<dim3(NDM / 128, ROWS / 128), 256, 0, stream>>>(attnb, woT, ROWS, NDM, NDM, bo, x, nullptr, tmp);
  ln_kernel<<<ROWS, 256, 0, stream>>>(tmp, ln1g, ln1b, x1f, x1b);

  // --- FFN
  gemm_bt<0><<<dim3(NRFF / 128, ROWS / 128), 256, 0, stream>>>(x1b, u1T, ROWS, NRFF, NDM, nullptr, nullptr, mid, nullptr);
  gemm_bt<2><<<dim3(NDFF / 128, ROWS / 128), 256, 0, stream>>>(mid, v1T, ROWS, NDFF, NRFF, b1, nullptr, hdn, nullptr);
  gemm_bt<0><<<dim3(NRFF / 128, ROWS / 128), 256, 0, stream>>>(hdn, u2T, ROWS, NRFF, NDFF, nullptr, nullptr, mid2, nullptr);
  gemm_bt<3><<<dim3(NDM / 128, ROWS / 128), 256, 0, stream>>>(mid2, v2T, ROWS, NDM, NRFF, b2, x1f, nullptr, tmp);

  // --- LN2 -> out (f32)
  ln_kernel<<<ROWS, 256, 0, stream>>>(tmp, ln2g, ln2b, out, nullptr);

  (void)in_sizes; (void)n_in; (void)out_size; (void)ws_size;
}

// Round 2
// 526.825 us; speedup vs baseline: 1.1803x; 1.1803x over previous
//
#include <hip/hip_runtime.h>
#include <hip/hip_bf16.h>

// ---------------------------------------------------------------------------
// FlashSVDBlockDA: low-rank transformer block on MI355X (gfx950)
// B=8 M=1024 DM=768 H=12 DH=64 R=32 RFF=384 DFF=3072 RWO=384
// R2: fold Wo via MFMA GEMM (was 113us scalar kernel); GEMM staging via
// global_load_lds width=16 with pre-swizzled global source.
// ---------------------------------------------------------------------------

typedef float f32x4 __attribute__((ext_vector_type(4)));
typedef __bf16 bf16x8 __attribute__((ext_vector_type(8)));

#define NB   8
#define NM   1024
#define NDM  768
#define NH   12
#define NDH  64
#define NR   32
#define NRFF 384
#define NDFF 3072
#define NRWO 384
#define ROWS (NB*NM)   // 8192
#define NQKV 2304      // 3*H*DH

// ---------------------------------------------------------------- small preps

__global__ void castb_kernel(const float* __restrict__ s, __hip_bfloat16* __restrict__ d, int n) {
  for (int i = blockIdx.x * blockDim.x + threadIdx.x; i < n; i += gridDim.x * blockDim.x)
    d[i] = __float2bfloat16(s[i]);
}

// dst[C][R] = cast(src[R][C])^T
__global__ void tcast_kernel(const float* __restrict__ src, __hip_bfloat16* __restrict__ dst, int R, int C) {
  int total = R * C;
  for (int i = blockIdx.x * blockDim.x + threadIdx.x; i < total; i += gridDim.x * blockDim.x) {
    int c = i / R, r = i - c * R;
    dst[i] = __float2bfloat16(src[(size_t)r * C + c]);
  }
}

// WqkvT[n][dm], n = t*768 + h*64 + dh ; W_t[h] = P_t[h] @ V_t[h]; also bqkv[n]
__global__ __launch_bounds__(256) void prep_wqkvT(
    const float* __restrict__ Pq, const float* __restrict__ Vq, const float* __restrict__ bq,
    const float* __restrict__ Pk, const float* __restrict__ Vk, const float* __restrict__ bk,
    const float* __restrict__ Pv, const float* __restrict__ Vv, const float* __restrict__ bv,
    __hip_bfloat16* __restrict__ wT, float* __restrict__ bqkv) {
  int n = blockIdx.x;
  int t = n / NDM, rem = n % NDM, h = rem >> 6, dh = rem & 63;
  const float* P = (t == 0) ? Pq : (t == 1) ? Pk : Pv;
  const float* V = (t == 0) ? Vq : (t == 1) ? Vk : Vv;
  const float* bb = (t == 0) ? bq : (t == 1) ? bk : bv;
  __shared__ float vcol[NR];
  if (threadIdx.x < NR) vcol[threadIdx.x] = V[((size_t)h * NR + threadIdx.x) * NDH + dh];
  __syncthreads();
  for (int dm = threadIdx.x; dm < NDM; dm += 256) {
    const float* pp = P + ((size_t)h * NDM + dm) * NR;
    float s = 0.f;
#pragma unroll
    for (int r = 0; r < NR; r++) s += pp[r] * vcol[r];
    wT[(size_t)n * NDM + dm] = __float2bfloat16(s);
  }
  if (threadIdx.x == 0) bqkv[n] = bb[h * NDH + dh];
}

// ---------------------------------------------------------------- GEMM (bf16)
// C[M][N] = A[M][K] @ Bt[N][K]^T, 128x128 tile, BK=64, 4 waves (2x2), each wave
// 64x64 out = 4x4 frags of 16x16x32 MFMA.
// Staging: global_load_lds dwordx4, LDS linear dest, PRE-SWIZZLED global source
// (kc = kcs ^ (row&7)); MFMA reads apply the same XOR on the byte offset.
// EPI: 0 = ->bf16 ; 1 = +bias ->bf16 ; 2 = gelu(+bias) ->bf16 ; 3 = +bias+resid ->f32
template <int EPI>
__global__ __launch_bounds__(256) void gemm_bt(
    const __hip_bfloat16* __restrict__ A, const __hip_bfloat16* __restrict__ Bt,
    int M, int N, int K,
    const float* __restrict__ bias, const float* __restrict__ resid,
    __hip_bfloat16* __restrict__ outb, float* __restrict__ outf) {
  __shared__ __align__(16) char lsA[128 * 128];
  __shared__ __align__(16) char lsB[128 * 128];
  const int tid = threadIdx.x;
  const int lane = tid & 63, wid = tid >> 6;
  const int wr = wid >> 1, wc = wid & 1;
  const int bm = blockIdx.y * 128, bn = blockIdx.x * 128;
  const int g = lane >> 4, q = lane & 15;

  // staging geometry: each wave owns 4 chunks of 1KB (8 rows) per buffer
  const int l3 = lane >> 3;            // 0..7  (= row&7 of this lane's row)
  const int kc = (lane & 7) ^ l3;      // pre-swizzled source k-chunk (8 bf16 each)

  f32x4 acc[4][4];
#pragma unroll
  for (int i = 0; i < 4; i++)
#pragma unroll
    for (int j = 0; j < 4; j++) acc[i][j] = f32x4{0.f, 0.f, 0.f, 0.f};

  for (int k0 = 0; k0 < K; k0 += 64) {
#pragma unroll
    for (int c = 0; c < 4; c++) {
      int chunk = wid * 4 + c;
      int row = chunk * 8 + l3;
      const __hip_bfloat16* ga = A + (size_t)(bm + row) * K + k0 + kc * 8;
      __builtin_amdgcn_global_load_lds(
          (const __attribute__((address_space(1))) void*)ga,
          (__attribute__((address_space(3))) void*)&lsA[chunk * 1024], 16, 0, 0);
      const __hip_bfloat16* gb = Bt + (size_t)(bn + row) * K + k0 + kc * 8;
      __builtin_amdgcn_global_load_lds(
          (const __attribute__((address_space(1))) void*)gb,
          (__attribute__((address_space(3))) void*)&lsB[chunk * 1024], 16, 0, 0);
    }
    __syncthreads();
#pragma unroll
    for (int ks = 0; ks < 2; ks++) {
      bf16x8 af[4], bfr[4];
#pragma unroll
      for (int i = 0; i < 4; i++) {
        int ra = wr * 64 + i * 16 + q;
        af[i] = *(const bf16x8*)&lsA[ra * 128 + ((ks * 64 + g * 16) ^ ((ra & 7) << 4))];
        int rb = wc * 64 + i * 16 + q;
        bfr[i] = *(const bf16x8*)&lsB[rb * 128 + ((ks * 64 + g * 16) ^ ((rb & 7) << 4))];
      }
#pragma unroll
      for (int i = 0; i < 4; i++)
#pragma unroll
        for (int j = 0; j < 4; j++)
          acc[i][j] = __builtin_amdgcn_mfma_f32_16x16x32_bf16(af[i], bfr[j], acc[i][j], 0, 0, 0);
    }
    __syncthreads();
  }

#pragma unroll
  for (int i = 0; i < 4; i++)
#pragma unroll
    for (int j = 0; j < 4; j++)
#pragma unroll
      for (int e = 0; e < 4; e++) {
        int row = bm + wr * 64 + i * 16 + g * 4 + e;
        int col = bn + wc * 64 + j * 16 + q;
        float v = acc[i][j][e];
        if (EPI == 1 || EPI == 2 || EPI == 3) v += bias[col];
        if (EPI == 2) v = 0.5f * v * (1.0f + erff(v * 0.70710678118654752f));
        if (EPI == 3) {
          v += resid[(size_t)row * N + col];
          outf[(size_t)row * N + col] = v;
        } else {
          outb[(size_t)row * N + col] = __float2bfloat16(v);
        }
      }
}

// ------------------------------------------------------------- flash attention
__global__ __launch_bounds__(256) void attn_kernel(const __hip_bfloat16* __restrict__ qkv,
                                                   const float* __restrict__ mask,
                                                   __hip_bfloat16* __restrict__ attnb) {
  __shared__ __align__(16) char Kl[64 * 128];
  __shared__ __align__(16) char Vl[64 * 128];   // transposed: [dh][n]
  __shared__ __align__(16) char Pl[4][16 * 128];
  const int blk = blockIdx.x;
  const int qb = blk & 15;
  const int h = (blk >> 4) % NH;
  const int b = blk / (16 * NH);
  const int tid = threadIdx.x;
  const int lane = tid & 63, w = tid >> 6;
  const int g = lane >> 4, q = lane & 15;
  const size_t rowbase = (size_t)b * NM;

  bf16x8 qf[2];
#pragma unroll
  for (int ks = 0; ks < 2; ks++)
    qf[ks] = *(const bf16x8*)(qkv + (rowbase + qb * 64 + w * 16 + q) * NQKV + h * 64 + g * 8 + ks * 32);

  f32x4 oacc[4];
#pragma unroll
  for (int dt = 0; dt < 4; dt++) oacc[dt] = f32x4{0.f, 0.f, 0.f, 0.f};
  float mrun[4] = {-1e30f, -1e30f, -1e30f, -1e30f};
  float lrun[4] = {0.f, 0.f, 0.f, 0.f};

  for (int t = 0; t < NM / 64; t++) {
    const int kv0 = t * 64;
#pragma unroll
    for (int i = 0; i < 2; i++) {
      int idx = tid + i * 256;
      int row = idx >> 3, kcc = idx & 7;
      uint4 v = *(const uint4*)(qkv + (rowbase + kv0 + row) * NQKV + NDM + h * 64 + kcc * 8);
      *(uint4*)&Kl[row * 128 + ((kcc * 16) ^ ((row & 7) << 4))] = v;
    }
#pragma unroll
    for (int i = 0; i < 2; i++) {
      int n = tid & 63;
      int dh0 = (tid >> 6) * 8 + i * 32;
      uint4 v = *(const uint4*)(qkv + (rowbase + kv0 + n) * NQKV + 2 * NDM + h * 64 + dh0);
      unsigned short us[8];
      *(uint4*)us = v;
#pragma unroll
      for (int j = 0; j < 8; j++) {
        int dh = dh0 + j;
        *(unsigned short*)&Vl[dh * 128 + ((n * 2) ^ ((dh & 7) << 4))] = us[j];
      }
    }
    __syncthreads();

    f32x4 sacc[4];
#pragma unroll
    for (int nt = 0; nt < 4; nt++) sacc[nt] = f32x4{0.f, 0.f, 0.f, 0.f};
#pragma unroll
    for (int ks = 0; ks < 2; ks++) {
#pragma unroll
      for (int nt = 0; nt < 4; nt++) {
        int r = nt * 16 + q;
        bf16x8 kf = *(const bf16x8*)&Kl[r * 128 + ((ks * 64 + g * 16) ^ ((r & 7) << 4))];
        sacc[nt] = __builtin_amdgcn_mfma_f32_16x16x32_bf16(qf[ks], kf, sacc[nt], 0, 0, 0);
      }
    }

    float mk[4];
#pragma unroll
    for (int nt = 0; nt < 4; nt++) mk[nt] = mask[b * NM + kv0 + nt * 16 + q];
    float pv[4][4];
    float mx[4];
#pragma unroll
    for (int e = 0; e < 4; e++) {
      float m0 = -1e30f;
#pragma unroll
      for (int nt = 0; nt < 4; nt++) {
        float s = sacc[nt][e] * 0.125f + mk[nt];
        pv[nt][e] = s;
        m0 = fmaxf(m0, s);
      }
      mx[e] = m0;
    }
#pragma unroll
    for (int d = 1; d < 16; d <<= 1)
#pragma unroll
      for (int e = 0; e < 4; e++) mx[e] = fmaxf(mx[e], __shfl_xor(mx[e], d));
    float corr[4], rs[4];
#pragma unroll
    for (int e = 0; e < 4; e++) {
      float mn = fmaxf(mrun[e], mx[e]);
      corr[e] = __expf(mrun[e] - mn);
      mrun[e] = mn;
    }
#pragma unroll
    for (int e = 0; e < 4; e++) {
      float s = 0.f;
#pragma unroll
      for (int nt = 0; nt < 4; nt++) {
        float p = __expf(pv[nt][e] - mrun[e]);
        pv[nt][e] = p;
        s += p;
      }
      rs[e] = s;
    }
#pragma unroll
    for (int d = 1; d < 16; d <<= 1)
#pragma unroll
      for (int e = 0; e < 4; e++) rs[e] += __shfl_xor(rs[e], d);
#pragma unroll
    for (int e = 0; e < 4; e++) lrun[e] = lrun[e] * corr[e] + rs[e];
#pragma unroll
    for (int dt = 0; dt < 4; dt++)
#pragma unroll
      for (int e = 0; e < 4; e++) oacc[dt][e] *= corr[e];

#pragma unroll
    for (int nt = 0; nt < 4; nt++)
#pragma unroll
      for (int e = 0; e < 4; e++) {
        int r = g * 4 + e;
        int colb = (nt * 16 + q) * 2;
        *(__hip_bfloat16*)&Pl[w][r * 128 + (colb ^ ((r & 7) << 4))] = __float2bfloat16(pv[nt][e]);
      }

#pragma unroll
    for (int ks = 0; ks < 2; ks++) {
      bf16x8 pf = *(const bf16x8*)&Pl[w][q * 128 + ((ks * 64 + g * 16) ^ ((q & 7) << 4))];
#pragma unroll
      for (int dt = 0; dt < 4; dt++) {
        int r = dt * 16 + q;
        bf16x8 vf = *(const bf16x8*)&Vl[r * 128 + ((ks * 64 + g * 16) ^ ((r & 7) << 4))];
        oacc[dt] = __builtin_amdgcn_mfma_f32_16x16x32_bf16(pf, vf, oacc[dt], 0, 0, 0);
      }
    }
    __syncthreads();
  }

#pragma unroll
  for (int dt = 0; dt < 4; dt++)
#pragma unroll
    for (int e = 0; e < 4; e++) {
      int r = g * 4 + e;
      int m = qb * 64 + w * 16 + r;
      int dh = dt * 16 + q;
      attnb[(rowbase + m) * NDM + h * 64 + dh] = __float2bfloat16(oacc[dt][e] / lrun[e]);
    }
}

// ------------------------------------------------------------------- layernorm
__global__ __launch_bounds__(256) void ln_kernel(const float* __restrict__ in, const float* __restrict__ gam,
                                                 const float* __restrict__ bet, float* __restrict__ outf,
                                                 __hip_bfloat16* __restrict__ outb) {
  const int row = blockIdx.x, tid = threadIdx.x;
  const float* p = in + (size_t)row * NDM;
  float v0 = p[tid], v1 = p[tid + 256], v2 = p[tid + 512];
  float s = v0 + v1 + v2, s2 = v0 * v0 + v1 * v1 + v2 * v2;
#pragma unroll
  for (int d = 1; d < 64; d <<= 1) {
    s += __shfl_xor(s, d);
    s2 += __shfl_xor(s2, d);
  }
  __shared__ float red[8];
  int w = tid >> 6;
  if ((tid & 63) == 0) { red[w] = s; red[4 + w] = s2; }
  __syncthreads();
  s = red[0] + red[1] + red[2] + red[3];
  s2 = red[4] + red[5] + red[6] + red[7];
  float mu = s * (1.0f / NDM);
  float var = fmaxf(s2 * (1.0f / NDM) - mu * mu, 0.0f);
  float rr = rsqrtf(var + 1e-12f);
  float o0 = (v0 - mu) * rr * gam[tid] + bet[tid];
  float o1 = (v1 - mu) * rr * gam[tid + 256] + bet[tid + 256];
  float o2 = (v2 - mu) * rr * gam[tid + 512] + bet[tid + 512];
  float* po = outf + (size_t)row * NDM;
  po[tid] = o0;
  po[tid + 256] = o1;
  po[tid + 512] = o2;
  if (outb) {
    __hip_bfloat16* pb = outb + (size_t)row * NDM;
    pb[tid] = __float2bfloat16(o0);
    pb[tid + 256] = __float2bfloat16(o1);
    pb[tid + 512] = __float2bfloat16(o2);
  }
}

// ------------------------------------------------------------------- launcher
extern "C" void kernel_launch(void* const* d_in, const int* in_sizes, int n_in,
                              void* d_out, int out_size, void* d_ws, size_t ws_size,
                              hipStream_t stream) {
  const float* x = (const float*)d_in[0];
  const float* mask = (const float*)d_in[1];
  const float* Pq = (const float*)d_in[2];
  const float* Vq = (const float*)d_in[3];
  const float* bq = (const float*)d_in[4];
  const float* Pk = (const float*)d_in[5];
  const float* Vk = (const float*)d_in[6];
  const float* bk = (const float*)d_in[7];
  const float* Pv = (const float*)d_in[8];
  const float* Vv = (const float*)d_in[9];
  const float* bv = (const float*)d_in[10];
  const float* Uo = (const float*)d_in[11];
  const float* Vo = (const float*)d_in[12];
  const float* bo = (const float*)d_in[13];
  const float* U1 = (const float*)d_in[14];
  const float* V1 = (const float*)d_in[15];
  const float* b1 = (const float*)d_in[16];
  const float* U2 = (const float*)d_in[17];
  const float* V2 = (const float*)d_in[18];
  const float* b2 = (const float*)d_in[19];
  const float* ln1g = (const float*)d_in[20];
  const float* ln1b = (const float*)d_in[21];
  const float* ln2g = (const float*)d_in[22];
  const float* ln2b = (const float*)d_in[23];
  float* out = (float*)d_out;
  char* ws = (char*)d_ws;

  size_t off = 0;
  auto alloc = [&](size_t bytes) { size_t o = off; off += (bytes + 255) & ~(size_t)255; return o; };
  const size_t o_xb    = alloc((size_t)ROWS * NDM * 2);
  const size_t o_wqkvT = alloc((size_t)NQKV * NDM * 2);
  const size_t o_bqkv  = alloc((size_t)NQKV * 4);
  const size_t o_woT   = alloc((size_t)NDM * NDM * 2);
  const size_t o_uoB   = alloc((size_t)NDM * NRWO * 2);
  const size_t o_voT   = alloc((size_t)NDM * NRWO * 2);
  const size_t o_u1T   = alloc((size_t)NRFF * NDM * 2);
  const size_t o_v1T   = alloc((size_t)NDFF * NRFF * 2);
  const size_t o_u2T   = alloc((size_t)NRFF * NDFF * 2);
  const size_t o_v2T   = alloc((size_t)NDM * NRFF * 2);
  const size_t o_qkv   = alloc((size_t)ROWS * NQKV * 2);   // 37.75 MB
  const size_t o_attnb = alloc((size_t)ROWS * NDM * 2);    // contiguous after qkv
  const size_t o_tmp   = alloc((size_t)ROWS * NDM * 4);
  const size_t o_x1f   = alloc((size_t)ROWS * NDM * 4);
  const size_t o_x1b   = alloc((size_t)ROWS * NDM * 2);
  const size_t o_mid   = alloc((size_t)ROWS * NRFF * 2);
  const size_t o_mid2  = alloc((size_t)ROWS * NRFF * 2);
  const size_t o_hdn   = o_qkv;  // hdn [8192][3072] bf16 reuses qkv+attnb (both dead)

  __hip_bfloat16* xb    = (__hip_bfloat16*)(ws + o_xb);
  __hip_bfloat16* wqkvT = (__hip_bfloat16*)(ws + o_wqkvT);
  float*          bqkv  = (float*)(ws + o_bqkv);
  __hip_bfloat16* woT   = (__hip_bfloat16*)(ws + o_woT);
  __hip_bfloat16* uoB   = (__hip_bfloat16*)(ws + o_uoB);
  __hip_bfloat16* voT   = (__hip_bfloat16*)(ws + o_voT);
  __hip_bfloat16* u1T   = (__hip_bfloat16*)(ws + o_u1T);
  __hip_bfloat16* v1T   = (__hip_bfloat16*)(ws + o_v1T);
  __hip_bfloat16* u2T   = (__hip_bfloat16*)(ws + o_u2T);
  __hip_bfloat16* v2T   = (__hip_bfloat16*)(ws + o_v2T);
  __hip_bfloat16* qkv   = (__hip_bfloat16*)(ws + o_qkv);
  __hip_bfloat16* attnb = (__hip_bfloat16*)(ws + o_attnb);
  float*          tmp   = (float*)(ws + o_tmp);
  float*          x1f   = (float*)(ws + o_x1f);
  __hip_bfloat16* x1b   = (__hip_bfloat16*)(ws + o_x1b);
  __hip_bfloat16* mid   = (__hip_bfloat16*)(ws + o_mid);
  __hip_bfloat16* mid2  = (__hip_bfloat16*)(ws + o_mid2);
  __hip_bfloat16* hdn   = (__hip_bfloat16*)(ws + o_hdn);

  // --- prep
  castb_kernel<<<1024, 256, 0, stream>>>(x, xb, ROWS * NDM);
  prep_wqkvT<<<NQKV, 256, 0, stream>>>(Pq, Vq, bq, Pk, Vk, bk, Pv, Vv, bv, wqkvT, bqkv);
  castb_kernel<<<256, 256, 0, stream>>>(Uo, uoB, NDM * NRWO);
  tcast_kernel<<<256, 256, 0, stream>>>(Vo, voT, NRWO, NDM);       // voT[768][384]
  tcast_kernel<<<1024, 256, 0, stream>>>(U1, u1T, NDM, NRFF);
  tcast_kernel<<<1024, 256, 0, stream>>>(V1, v1T, NRFF, NDFF);
  tcast_kernel<<<1024, 256, 0, stream>>>(U2, u2T, NDFF, NRFF);
  tcast_kernel<<<1024, 256, 0, stream>>>(V2, v2T, NRFF, NDM);

  // --- WoT[n][k] = sum_r voT[n][r] * Uo[k][r]  (MFMA fold, was 113us scalar)
  gemm_bt<0><<<dim3(NDM / 128, NDM / 128), 256, 0, stream>>>(voT, uoB, NDM, NDM, NRWO, nullptr, nullptr, woT, nullptr);

  // --- QKV = xb @ WqkvT^T + bqkv
  gemm_bt<1><<<dim3(NQKV / 128, ROWS / 128), 256, 0, stream>>>(xb, wqkvT, ROWS, NQKV, NDM, bqkv, nullptr, qkv, nullptr);

  // --- attention
  attn_kernel<<<NB * NH * (NM / 64), 256, 0, stream>>>(qkv, mask, attnb);

  // --- Wo proj + bias + residual(x) -> tmp(f32); LN1 -> x1f, x1b
  gemm_bt<3><<<dim3(NDM / 128, ROWS / 128), 256, 0, stream>>>(attnb, woT, ROWS, NDM, NDM, bo, x, nullptr, tmp);
  ln_kernel<<<ROWS, 256, 0, stream>>>(tmp, ln1g, ln1b, x1f, x1b);

  // --- FFN
  gemm_bt<0><<<dim3(NRFF / 128, ROWS / 128), 256, 0, stream>>>(x1b, u1T, ROWS, NRFF, NDM, nullptr, nullptr, mid, nullptr);
  gemm_bt<2><<<dim3(NDFF / 128, ROWS / 128), 256, 0, stream>>>(mid, v1T, ROWS, NDFF, NRFF, b1, nullptr, hdn, nullptr);
  gemm_bt<0><<<dim3(NRFF / 128, ROWS / 128), 256, 0, stream>>>(hdn, u2T, ROWS, NRFF, NDFF, nullptr, nullptr, mid2, nullptr);
  gemm_bt<3><<<dim3(NDM / 128, ROWS / 128), 256, 0, stream>>>(mid2, v2T, ROWS, NDM, NRFF, b2, x1f, nullptr, tmp);

  // --- LN2 -> out (f32)
  ln_kernel<<<ROWS, 256, 0, stream>>>(tmp, ln2g, ln2b, out, nullptr);

  (void)in_sizes; (void)n_in; (void)out_size; (void)ws_size;
}

// Round 3
// 515.151 us; speedup vs baseline: 1.2071x; 1.0227x over previous
//
#include <hip/hip_runtime.h>
#include <hip/hip_bf16.h>

// ---------------------------------------------------------------------------
// FlashSVDBlockDA: low-rank transformer block on MI355X (gfx950)
// R3: attention rewrite — swapped QK^T (in-lane softmax), V pre-transposed in
// QKV-GEMM epilogue, K/V staged via global_load_lds, 2-phase prefetch,
// XCD-aware block swizzle everywhere.
// ---------------------------------------------------------------------------

typedef float f32x4 __attribute__((ext_vector_type(4)));
typedef __bf16 bf16x8 __attribute__((ext_vector_type(8)));

#define NB   8
#define NM   1024
#define NDM  768
#define NH   12
#define NDH  64
#define NR   32
#define NRFF 384
#define NDFF 3072
#define NRWO 384
#define ROWS (NB*NM)   // 8192
#define NQKV 2304      // 3*H*DH
#define NQK  1536      // Q+K packed row stride

__device__ __forceinline__ float fexp2(float x) {
#if __has_builtin(__builtin_amdgcn_exp2f)
  return __builtin_amdgcn_exp2f(x);
#else
  return exp2f(x);
#endif
}

__device__ __forceinline__ unsigned short f2bf(float f) {
  __hip_bfloat16 h = __float2bfloat16(f);
  return *reinterpret_cast<unsigned short*>(&h);
}

// bijective XCD swizzle: contiguous chunks of the original id space per XCD
__device__ __forceinline__ int xcd_swizzle(int orig, int nwg) {
  int q = nwg >> 3, r = nwg & 7;
  int xcd = orig & 7, idx = orig >> 3;
  return (xcd < r ? xcd * (q + 1) : r * (q + 1) + (xcd - r) * q) + idx;
}

// ---------------------------------------------------------------- small preps

__global__ void castb_kernel(const float* __restrict__ s, __hip_bfloat16* __restrict__ d, int n) {
  for (int i = blockIdx.x * blockDim.x + threadIdx.x; i < n; i += gridDim.x * blockDim.x)
    d[i] = __float2bfloat16(s[i]);
}

// dst[C][R] = cast(src[R][C])^T
__global__ void tcast_kernel(const float* __restrict__ src, __hip_bfloat16* __restrict__ dst, int R, int C) {
  int total = R * C;
  for (int i = blockIdx.x * blockDim.x + threadIdx.x; i < total; i += gridDim.x * blockDim.x) {
    int c = i / R, r = i - c * R;
    dst[i] = __float2bfloat16(src[(size_t)r * C + c]);
  }
}

// WqkvT[n][dm], n = t*768 + h*64 + dh ; W_t[h] = P_t[h] @ V_t[h]; also bqkv[n]
__global__ __launch_bounds__(256) void prep_wqkvT(
    const float* __restrict__ Pq, const float* __restrict__ Vq, const float* __restrict__ bq,
    const float* __restrict__ Pk, const float* __restrict__ Vk, const float* __restrict__ bk,
    const float* __restrict__ Pv, const float* __restrict__ Vv, const float* __restrict__ bv,
    __hip_bfloat16* __restrict__ wT, float* __restrict__ bqkv) {
  int n = blockIdx.x;
  int t = n / NDM, rem = n % NDM, h = rem >> 6, dh = rem & 63;
  const float* P = (t == 0) ? Pq : (t == 1) ? Pk : Pv;
  const float* V = (t == 0) ? Vq : (t == 1) ? Vk : Vv;
  const float* bb = (t == 0) ? bq : (t == 1) ? bk : bv;
  __shared__ float vcol[NR];
  if (threadIdx.x < NR) vcol[threadIdx.x] = V[((size_t)h * NR + threadIdx.x) * NDH + dh];
  __syncthreads();
  for (int dm = threadIdx.x; dm < NDM; dm += 256) {
    const float* pp = P + ((size_t)h * NDM + dm) * NR;
    float s = 0.f;
#pragma unroll
    for (int r = 0; r < NR; r++) s += pp[r] * vcol[r];
    wT[(size_t)n * NDM + dm] = __float2bfloat16(s);
  }
  if (threadIdx.x == 0) bqkv[n] = bb[h * NDH + dh];
}

// ---------------------------------------------------------------- GEMM (bf16)
// C[M][N] = A[M][K] @ Bt[N][K]^T, 128x128 tile, BK=64, 4 waves (2x2).
// EPI: 0 ->bf16 ; 1 +bias ->bf16 ; 2 gelu(+bias) ->bf16 ; 3 +bias+resid ->f32
//      4 QKV special: cols<1536 -> outb[row*1536+col]; cols>=1536 -> vt scatter
template <int EPI>
__global__ __launch_bounds__(256) void gemm_bt(
    const __hip_bfloat16* __restrict__ A, const __hip_bfloat16* __restrict__ Bt,
    int M, int N, int K,
    const float* __restrict__ bias, const float* __restrict__ resid,
    __hip_bfloat16* __restrict__ outb, float* __restrict__ outf,
    __hip_bfloat16* __restrict__ vtout) {
  __shared__ __align__(16) char lsA[128 * 128];
  __shared__ __align__(16) char lsB[128 * 128];
  const int tid = threadIdx.x;
  const int lane = tid & 63, wid = tid >> 6;
  const int wr = wid >> 1, wc = wid & 1;
  const int gx = gridDim.x;
  const int wg = xcd_swizzle(blockIdx.y * gx + blockIdx.x, gx * gridDim.y);
  const int bm = (wg / gx) * 128, bn = (wg % gx) * 128;
  const int g = lane >> 4, q = lane & 15;

  const int l3 = lane >> 3;
  const int kc = (lane & 7) ^ l3;

  f32x4 acc[4][4];
#pragma unroll
  for (int i = 0; i < 4; i++)
#pragma unroll
    for (int j = 0; j < 4; j++) acc[i][j] = f32x4{0.f, 0.f, 0.f, 0.f};

  for (int k0 = 0; k0 < K; k0 += 64) {
#pragma unroll
    for (int c = 0; c < 4; c++) {
      int chunk = wid * 4 + c;
      int row = chunk * 8 + l3;
      const __hip_bfloat16* ga = A + (size_t)(bm + row) * K + k0 + kc * 8;
      __builtin_amdgcn_global_load_lds(
          (const __attribute__((address_space(1))) void*)ga,
          (__attribute__((address_space(3))) void*)&lsA[chunk * 1024], 16, 0, 0);
      const __hip_bfloat16* gb = Bt + (size_t)(bn + row) * K + k0 + kc * 8;
      __builtin_amdgcn_global_load_lds(
          (const __attribute__((address_space(1))) void*)gb,
          (__attribute__((address_space(3))) void*)&lsB[chunk * 1024], 16, 0, 0);
    }
    __syncthreads();
#pragma unroll
    for (int ks = 0; ks < 2; ks++) {
      bf16x8 af[4], bfr[4];
#pragma unroll
      for (int i = 0; i < 4; i++) {
        int ra = wr * 64 + i * 16 + q;
        af[i] = *(const bf16x8*)&lsA[ra * 128 + ((ks * 64 + g * 16) ^ ((ra & 7) << 4))];
        int rb = wc * 64 + i * 16 + q;
        bfr[i] = *(const bf16x8*)&lsB[rb * 128 + ((ks * 64 + g * 16) ^ ((rb & 7) << 4))];
      }
#pragma unroll
      for (int i = 0; i < 4; i++)
#pragma unroll
        for (int j = 0; j < 4; j++)
          acc[i][j] = __builtin_amdgcn_mfma_f32_16x16x32_bf16(af[i], bfr[j], acc[i][j], 0, 0, 0);
    }
    __syncthreads();
  }

#pragma unroll
  for (int i = 0; i < 4; i++)
#pragma unroll
    for (int j = 0; j < 4; j++)
#pragma unroll
      for (int e = 0; e < 4; e++) {
        int row = bm + wr * 64 + i * 16 + g * 4 + e;
        int col = bn + wc * 64 + j * 16 + q;
        float v = acc[i][j][e];
        if (EPI == 1 || EPI == 2 || EPI == 3 || EPI == 4) v += bias[col];
        if (EPI == 2) v = 0.5f * v * (1.0f + erff(v * 0.70710678118654752f));
        if (EPI == 3) {
          v += resid[(size_t)row * N + col];
          outf[(size_t)row * N + col] = v;
        } else if (EPI == 4) {
          if (col < NQK) {
            outb[(size_t)row * NQK + col] = __float2bfloat16(v);
          } else {
            int cv = col - NQK;
            int b = row >> 10, m = row & 1023;
            int h = cv >> 6, dh = cv & 63;
            vtout[(((size_t)b * NH + h) * NDH + dh) * NM + m] = __float2bfloat16(v);
          }
        } else {
          outb[(size_t)row * N + col] = __float2bfloat16(v);
        }
      }
}

// ------------------------------------------------------------- flash attention
// Per block: one (b, h, 64-row Q tile). 4 waves x 16 rows. KV tiles of 64,
// double-buffered, staged via global_load_lds (pre-swizzled source).
// Swapped QK^T: sacc = mfma(K, Q) => lane holds S[m=q][kv=nt*16+4g+e]:
// softmax reduction = 15 in-lane + 2 shfl. P written as 4x ds_write_b64.
__global__ __launch_bounds__(256) void attn_kernel(const __hip_bfloat16* __restrict__ qk,
                                                   const __hip_bfloat16* __restrict__ vt,
                                                   const float* __restrict__ mask,
                                                   __hip_bfloat16* __restrict__ attnb) {
  __shared__ __align__(16) char Kl[2][64 * 128];
  __shared__ __align__(16) char Vl[2][64 * 128];   // row = dh, col = n (2B)
  __shared__ __align__(16) char Pl[4][16 * 128];   // row = m(16), col = kv
  const int nblk = NB * NH * (NM / 64);
  const int blk = xcd_swizzle(blockIdx.x, nblk);
  const int qb = blk & 15;
  const int h = (blk >> 4) % NH;
  const int b = blk / (16 * NH);
  const int tid = threadIdx.x;
  const int lane = tid & 63, w = tid >> 6;
  const int g = lane >> 4, q = lane & 15;
  const size_t rowbase = (size_t)b * NM;
  const float S2 = 0.125f * 1.44269504088896f;   // scale * log2(e)
  const float L2E = 1.44269504088896f;

  const __hip_bfloat16* Kbase = qk + rowbase * NQK + NDM + h * 64;
  const __hip_bfloat16* Vbase = vt + ((size_t)(b * NH + h) * NDH) * NM;

  bf16x8 qf[2];
#pragma unroll
  for (int ks = 0; ks < 2; ks++)
    qf[ks] = *(const bf16x8*)(qk + (rowbase + qb * 64 + w * 16 + q) * NQK + h * 64 + g * 8 + ks * 32);

  const int l3 = lane >> 3;
  const int kc = (lane & 7) ^ l3;

  // stage KV tile t into buffer buf (4 global_load_lds per wave)
  auto stage = [&](int buf, int t) {
    const int kv0 = t * 64;
#pragma unroll
    for (int c = 0; c < 2; c++) {
      int r8 = w * 16 + c * 8;
      int row = r8 + l3;
      const __hip_bfloat16* gk = Kbase + (size_t)(kv0 + row) * NQK + kc * 8;
      __builtin_amdgcn_global_load_lds(
          (const __attribute__((address_space(1))) void*)gk,
          (__attribute__((address_space(3))) void*)&Kl[buf][r8 * 128], 16, 0, 0);
      const __hip_bfloat16* gv = Vbase + (size_t)row * NM + kv0 + kc * 8;
      __builtin_amdgcn_global_load_lds(
          (const __attribute__((address_space(1))) void*)gv,
          (__attribute__((address_space(3))) void*)&Vl[buf][r8 * 128], 16, 0, 0);
    }
  };

  f32x4 oacc[4];
#pragma unroll
  for (int dt = 0; dt < 4; dt++) oacc[dt] = f32x4{0.f, 0.f, 0.f, 0.f};
  float mrun = -1e30f, lrun = 0.f;

  stage(0, 0);
  __syncthreads();

  for (int t = 0; t < NM / 64; t++) {
    const int cur = t & 1;
    if (t + 1 < NM / 64) stage(cur ^ 1, t + 1);
    const int kv0 = t * 64;

    // S^T = K Q^T : sacc[nt][e] = S[m=q][kv = nt*16 + 4g + e]
    f32x4 sacc[4];
#pragma unroll
    for (int nt = 0; nt < 4; nt++) sacc[nt] = f32x4{0.f, 0.f, 0.f, 0.f};
#pragma unroll
    for (int ks = 0; ks < 2; ks++) {
#pragma unroll
      for (int nt = 0; nt < 4; nt++) {
        int r = nt * 16 + q;
        bf16x8 kf = *(const bf16x8*)&Kl[cur][r * 128 + ((ks * 64 + g * 16) ^ ((r & 7) << 4))];
        sacc[nt] = __builtin_amdgcn_mfma_f32_16x16x32_bf16(kf, qf[ks], sacc[nt], 0, 0, 0);
      }
    }

    // scaled logits in log2 space + mask
    float zs[4][4];
    float mx = -1e30f;
#pragma unroll
    for (int nt = 0; nt < 4; nt++) {
      const float4 mk = *(const float4*)(mask + b * NM + kv0 + nt * 16 + g * 4);
      zs[nt][0] = sacc[nt][0] * S2 + mk.x * L2E;
      zs[nt][1] = sacc[nt][1] * S2 + mk.y * L2E;
      zs[nt][2] = sacc[nt][2] * S2 + mk.z * L2E;
      zs[nt][3] = sacc[nt][3] * S2 + mk.w * L2E;
#pragma unroll
      for (int e = 0; e < 4; e++) mx = fmaxf(mx, zs[nt][e]);
    }
    mx = fmaxf(mx, __shfl_xor(mx, 16));
    mx = fmaxf(mx, __shfl_xor(mx, 32));

    float mnew = fmaxf(mrun, mx);
    float corr = fexp2(mrun - mnew);
    mrun = mnew;

    float rsum = 0.f;
    float p[4][4];
#pragma unroll
    for (int nt = 0; nt < 4; nt++)
#pragma unroll
      for (int e = 0; e < 4; e++) {
        float pe = fexp2(zs[nt][e] - mrun);
        p[nt][e] = pe;
        rsum += pe;
      }
    rsum += __shfl_xor(rsum, 16);
    rsum += __shfl_xor(rsum, 32);
    lrun = lrun * corr + rsum;

    // bridge corr from q-space to PV row space (m = 4g + e)
    float corrm[4];
#pragma unroll
    for (int e = 0; e < 4; e++) corrm[e] = __shfl(corr, g * 4 + e);
#pragma unroll
    for (int dt = 0; dt < 4; dt++)
#pragma unroll
      for (int e = 0; e < 4; e++) oacc[dt][e] *= corrm[e];

    // write P[m=q][kv] : 4x 8B swizzled writes
#pragma unroll
    for (int nt = 0; nt < 4; nt++) {
      ushort4 pk;
      pk.x = f2bf(p[nt][0]);
      pk.y = f2bf(p[nt][1]);
      pk.z = f2bf(p[nt][2]);
      pk.w = f2bf(p[nt][3]);
      *(ushort4*)&Pl[w][q * 128 + ((nt * 32 + g * 8) ^ ((q & 7) << 4))] = pk;
    }

    // O += P @ V
#pragma unroll
    for (int ks = 0; ks < 2; ks++) {
      bf16x8 pf = *(const bf16x8*)&Pl[w][q * 128 + ((ks * 64 + g * 16) ^ ((q & 7) << 4))];
#pragma unroll
      for (int dt = 0; dt < 4; dt++) {
        int r = dt * 16 + q;
        bf16x8 vf = *(const bf16x8*)&Vl[cur][r * 128 + ((ks * 64 + g * 16) ^ ((r & 7) << 4))];
        oacc[dt] = __builtin_amdgcn_mfma_f32_16x16x32_bf16(pf, vf, oacc[dt], 0, 0, 0);
      }
    }
    __syncthreads();
  }

  // final normalize + store: O rows m = 4g+e, cols dh = dt*16+q
  float lm[4];
#pragma unroll
  for (int e = 0; e < 4; e++) lm[e] = 1.0f / __shfl(lrun, g * 4 + e);
#pragma unroll
  for (int dt = 0; dt < 4; dt++)
#pragma unroll
    for (int e = 0; e < 4; e++) {
      int m = qb * 64 + w * 16 + g * 4 + e;
      int dh = dt * 16 + q;
      attnb[(rowbase + m) * NDM + h * 64 + dh] = __float2bfloat16(oacc[dt][e] * lm[e]);
    }
}

// ------------------------------------------------------------------- layernorm
__global__ __launch_bounds__(256) void ln_kernel(const float* __restrict__ in, const float* __restrict__ gam,
                                                 const float* __restrict__ bet, float* __restrict__ outf,
                                                 __hip_bfloat16* __restrict__ outb) {
  const int row = blockIdx.x, tid = threadIdx.x;
  const float* p = in + (size_t)row * NDM;
  float v0 = p[tid], v1 = p[tid + 256], v2 = p[tid + 512];
  float s = v0 + v1 + v2, s2 = v0 * v0 + v1 * v1 + v2 * v2;
#pragma unroll
  for (int d = 1; d < 64; d <<= 1) {
    s += __shfl_xor(s, d);
    s2 += __shfl_xor(s2, d);
  }
  __shared__ float red[8];
  int w = tid >> 6;
  if ((tid & 63) == 0) { red[w] = s; red[4 + w] = s2; }
  __syncthreads();
  s = red[0] + red[1] + red[2] + red[3];
  s2 = red[4] + red[5] + red[6] + red[7];
  float mu = s * (1.0f / NDM);
  float var = fmaxf(s2 * (1.0f / NDM) - mu * mu, 0.0f);
  float rr = rsqrtf(var + 1e-12f);
  float o0 = (v0 - mu) * rr * gam[tid] + bet[tid];
  float o1 = (v1 - mu) * rr * gam[tid + 256] + bet[tid + 256];
  float o2 = (v2 - mu) * rr * gam[tid + 512] + bet[tid + 512];
  float* po = outf + (size_t)row * NDM;
  po[tid] = o0;
  po[tid + 256] = o1;
  po[tid + 512] = o2;
  if (outb) {
    __hip_bfloat16* pb = outb + (size_t)row * NDM;
    pb[tid] = __float2bfloat16(o0);
    pb[tid + 256] = __float2bfloat16(o1);
    pb[tid + 512] = __float2bfloat16(o2);
  }
}

// ------------------------------------------------------------------- launcher
extern "C" void kernel_launch(void* const* d_in, const int* in_sizes, int n_in,
                              void* d_out, int out_size, void* d_ws, size_t ws_size,
                              hipStream_t stream) {
  const float* x = (const float*)d_in[0];
  const float* mask = (const float*)d_in[1];
  const float* Pq = (const float*)d_in[2];
  const float* Vq = (const float*)d_in[3];
  const float* bq = (const float*)d_in[4];
  const float* Pk = (const float*)d_in[5];
  const float* Vk = (const float*)d_in[6];
  const float* bk = (const float*)d_in[7];
  const float* Pv = (const float*)d_in[8];
  const float* Vv = (const float*)d_in[9];
  const float* bv = (const float*)d_in[10];
  const float* Uo = (const float*)d_in[11];
  const float* Vo = (const float*)d_in[12];
  const float* bo = (const float*)d_in[13];
  const float* U1 = (const float*)d_in[14];
  const float* V1 = (const float*)d_in[15];
  const float* b1 = (const float*)d_in[16];
  const float* U2 = (const float*)d_in[17];
  const float* V2 = (const float*)d_in[18];
  const float* b2 = (const float*)d_in[19];
  const float* ln1g = (const float*)d_in[20];
  const float* ln1b = (const float*)d_in[21];
  const float* ln2g = (const float*)d_in[22];
  const float* ln2b = (const float*)d_in[23];
  float* out = (float*)d_out;
  char* ws = (char*)d_ws;

  size_t off = 0;
  auto alloc = [&](size_t bytes) { size_t o = off; off += (bytes + 255) & ~(size_t)255; return o; };
  const size_t o_xb    = alloc((size_t)ROWS * NDM * 2);
  const size_t o_wqkvT = alloc((size_t)NQKV * NDM * 2);
  const size_t o_bqkv  = alloc((size_t)NQKV * 4);
  const size_t o_woT   = alloc((size_t)NDM * NDM * 2);
  const size_t o_uoB   = alloc((size_t)NDM * NRWO * 2);
  const size_t o_voT   = alloc((size_t)NDM * NRWO * 2);
  const size_t o_u1T   = alloc((size_t)NRFF * NDM * 2);
  const size_t o_v1T   = alloc((size_t)NDFF * NRFF * 2);
  const size_t o_u2T   = alloc((size_t)NRFF * NDFF * 2);
  const size_t o_v2T   = alloc((size_t)NDM * NRFF * 2);
  const size_t o_qk    = alloc((size_t)ROWS * NQK * 2);            // 25.2 MB
  const size_t o_vt    = alloc((size_t)NB * NH * NDH * NM * 2);    // 12.6 MB
  const size_t o_attnb = alloc((size_t)ROWS * NDM * 2);            // 12.6 MB
  const size_t o_tmp   = alloc((size_t)ROWS * NDM * 4);
  const size_t o_x1f   = alloc((size_t)ROWS * NDM * 4);
  const size_t o_x1b   = alloc((size_t)ROWS * NDM * 2);
  const size_t o_mid   = alloc((size_t)ROWS * NRFF * 2);
  const size_t o_mid2  = alloc((size_t)ROWS * NRFF * 2);
  const size_t o_hdn   = o_qk;  // hdn [8192][3072] bf16 (50.3MB) over qk+vt+attnb (dead)

  __hip_bfloat16* xb    = (__hip_bfloat16*)(ws + o_xb);
  __hip_bfloat16* wqkvT = (__hip_bfloat16*)(ws + o_wqkvT);
  float*          bqkv  = (float*)(ws + o_bqkv);
  __hip_bfloat16* woT   = (__hip_bfloat16*)(ws + o_woT);
  __hip_bfloat16* uoB   = (__hip_bfloat16*)(ws + o_uoB);
  __hip_bfloat16* voT   = (__hip_bfloat16*)(ws + o_voT);
  __hip_bfloat16* u1T   = (__hip_bfloat16*)(ws + o_u1T);
  __hip_bfloat16* v1T   = (__hip_bfloat16*)(ws + o_v1T);
  __hip_bfloat16* u2T   = (__hip_bfloat16*)(ws + o_u2T);
  __hip_bfloat16* v2T   = (__hip_bfloat16*)(ws + o_v2T);
  __hip_bfloat16* qkb   = (__hip_bfloat16*)(ws + o_qk);
  __hip_bfloat16* vt    = (__hip_bfloat16*)(ws + o_vt);
  __hip_bfloat16* attnb = (__hip_bfloat16*)(ws + o_attnb);
  float*          tmp   = (float*)(ws + o_tmp);
  float*          x1f   = (float*)(ws + o_x1f);
  __hip_bfloat16* x1b   = (__hip_bfloat16*)(ws + o_x1b);
  __hip_bfloat16* mid   = (__hip_bfloat16*)(ws + o_mid);
  __hip_bfloat16* mid2  = (__hip_bfloat16*)(ws + o_mid2);
  __hip_bfloat16* hdn   = (__hip_bfloat16*)(ws + o_hdn);

  // --- prep
  castb_kernel<<<1024, 256, 0, stream>>>(x, xb, ROWS * NDM);
  prep_wqkvT<<<NQKV, 256, 0, stream>>>(Pq, Vq, bq, Pk, Vk, bk, Pv, Vv, bv, wqkvT, bqkv);
  castb_kernel<<<256, 256, 0, stream>>>(Uo, uoB, NDM * NRWO);
  tcast_kernel<<<256, 256, 0, stream>>>(Vo, voT, NRWO, NDM);
  tcast_kernel<<<1024, 256, 0, stream>>>(U1, u1T, NDM, NRFF);
  tcast_kernel<<<1024, 256, 0, stream>>>(V1, v1T, NRFF, NDFF);
  tcast_kernel<<<1024, 256, 0, stream>>>(U2, u2T, NDFF, NRFF);
  tcast_kernel<<<1024, 256, 0, stream>>>(V2, v2T, NRFF, NDM);

  // --- WoT[n][k] = sum_r voT[n][r] * Uo[k][r]
  gemm_bt<0><<<dim3(NDM / 128, NDM / 128), 256, 0, stream>>>(voT, uoB, NDM, NDM, NRWO, nullptr, nullptr, woT, nullptr, nullptr);

  // --- QKV: Q/K -> qkb[8192][1536], V -> vt[b][h][dh][m]
  gemm_bt<4><<<dim3(NQKV / 128, ROWS / 128), 256, 0, stream>>>(xb, wqkvT, ROWS, NQKV, NDM, bqkv, nullptr, qkb, nullptr, vt);

  // --- attention
  attn_kernel<<<NB * NH * (NM / 64), 256, 0, stream>>>(qkb, vt, mask, attnb);

  // --- Wo proj + bias + residual(x) -> tmp(f32); LN1 -> x1f, x1b
  gemm_bt<3><<<dim3(NDM / 128, ROWS / 128), 256, 0, stream>>>(attnb, woT, ROWS, NDM, NDM, bo, x, nullptr, tmp, nullptr);
  ln_kernel<<<ROWS, 256, 0, stream>>>(tmp, ln1g, ln1b, x1f, x1b);

  // --- FFN
  gemm_bt<0><<<dim3(NRFF / 128, ROWS / 128), 256, 0, stream>>>(x1b, u1T, ROWS, NRFF, NDM, nullptr, nullptr, mid, nullptr, nullptr);
  gemm_bt<2><<<dim3(NDFF / 128, ROWS / 128), 256, 0, stream>>>(mid, v1T, ROWS, NDFF, NRFF, b1, nullptr, hdn, nullptr, nullptr);
  gemm_bt<0><<<dim3(NRFF / 128, ROWS / 128), 256, 0, stream>>>(hdn, u2T, ROWS, NRFF, NDFF, nullptr, nullptr, mid2, nullptr, nullptr);
  gemm_bt<3><<<dim3(NDM / 128, ROWS / 128), 256, 0, stream>>>(mid2, v2T, ROWS, NDM, NRFF, b2, x1f, nullptr, tmp, nullptr);

  // --- LN2 -> out (f32)
  ln_kernel<<<ROWS, 256, 0, stream>>>(tmp, ln2g, ln2b, out, nullptr);

  (void)in_sizes; (void)n_in; (void)out_size; (void)ws_size;
}

// Round 6
// 439.626 us; speedup vs baseline: 1.4144x; 1.1718x over previous
//
#include <hip/hip_runtime.h>
#include <hip/hip_bf16.h>

// ---------------------------------------------------------------------------
// FlashSVDBlockDA: low-rank transformer block on MI355X (gfx950)
// R5 = R4 with the B-tile staging loop bound fixed (BNt/32 chunks per wave;
// R4 staged only half of lsB -> NaN). Resubmitted after broker timeout.
// ---------------------------------------------------------------------------

typedef float f32x4 __attribute__((ext_vector_type(4)));
typedef __bf16 bf16x8 __attribute__((ext_vector_type(8)));

#define NB   8
#define NM   1024
#define NDM  768
#define NH   12
#define NDH  64
#define NR   32
#define NRFF 384
#define NDFF 3072
#define NRWO 384
#define ROWS (NB*NM)   // 8192
#define NQKV 2304      // 3*H*DH
#define NQK  1536      // Q+K packed row stride

__device__ __forceinline__ float fexp2(float x) {
#if __has_builtin(__builtin_amdgcn_exp2f)
  return __builtin_amdgcn_exp2f(x);
#else
  return exp2f(x);
#endif
}

__device__ __forceinline__ unsigned short f2bf(float f) {
  __hip_bfloat16 h = __float2bfloat16(f);
  return *reinterpret_cast<unsigned short*>(&h);
}

// bijective XCD swizzle
__device__ __forceinline__ int xcd_swizzle(int orig, int nwg) {
  int q = nwg >> 3, r = nwg & 7;
  int xcd = orig & 7, idx = orig >> 3;
  return (xcd < r ? xcd * (q + 1) : r * (q + 1) + (xcd - r) * q) + idx;
}

// ------------------------------------------------- elementwise prep (1 kernel)
__global__ void prep_elem(const float* __restrict__ x, const float* __restrict__ Uo,
                          const float* __restrict__ mask,
                          __hip_bfloat16* __restrict__ xb, __hip_bfloat16* __restrict__ uoB,
                          float* __restrict__ mask2) {
  const int NX = 1572864, NU = 73728, NMK = 2048;
  for (int i = blockIdx.x * blockDim.x + threadIdx.x; i < NX + NU + NMK;
       i += gridDim.x * blockDim.x) {
    if (i < NX) {
      float4 v = ((const float4*)x)[i];
      ushort4 o = {f2bf(v.x), f2bf(v.y), f2bf(v.z), f2bf(v.w)};
      ((ushort4*)xb)[i] = o;
    } else if (i < NX + NU) {
      int j = i - NX;
      float4 v = ((const float4*)Uo)[j];
      ushort4 o = {f2bf(v.x), f2bf(v.y), f2bf(v.z), f2bf(v.w)};
      ((ushort4*)uoB)[j] = o;
    } else {
      int j = i - NX - NU;
      float4 v = ((const float4*)mask)[j];
      const float L = 1.44269504088896f;
      float4 o = {v.x * L, v.y * L, v.z * L, v.w * L};
      ((float4*)mask2)[j] = o;
    }
  }
}

// ------------------------------------------------- tiled transpose-casts
__global__ __launch_bounds__(256) void prep_tT(
    const float* __restrict__ Vo, const float* __restrict__ U1, const float* __restrict__ V1,
    const float* __restrict__ U2, const float* __restrict__ V2,
    __hip_bfloat16* __restrict__ voT, __hip_bfloat16* __restrict__ u1T,
    __hip_bfloat16* __restrict__ v1T, __hip_bfloat16* __restrict__ u2T,
    __hip_bfloat16* __restrict__ v2T) {
  int blk = blockIdx.x;
  const float* src; __hip_bfloat16* dst; int R, C, lid;
  if (blk < 72)        { src = Vo; dst = voT; R = 384;  C = 768;  lid = blk; }
  else if (blk < 144)  { src = U1; dst = u1T; R = 768;  C = 384;  lid = blk - 72; }
  else if (blk < 432)  { src = V1; dst = v1T; R = 384;  C = 3072; lid = blk - 144; }
  else if (blk < 720)  { src = U2; dst = u2T; R = 3072; C = 384;  lid = blk - 432; }
  else                 { src = V2; dst = v2T; R = 384;  C = 768;  lid = blk - 720; }
  int tilesC = C >> 6;
  int tr = lid / tilesC, tc = lid - tr * tilesC;
  int r0 = tr << 6, c0 = tc << 6;
  __shared__ float sm[64][65];
  int tx = threadIdx.x & 63, ty = threadIdx.x >> 6;
#pragma unroll
  for (int k = 0; k < 16; k++) {
    int rr = ty * 16 + k;
    sm[rr][tx] = src[(size_t)(r0 + rr) * C + c0 + tx];
  }
  __syncthreads();
#pragma unroll
  for (int k = 0; k < 16; k++) {
    int cc = ty * 16 + k;
    dst[(size_t)(c0 + cc) * R + r0 + tx] = __float2bfloat16(sm[tx][cc]);
  }
}

// ------------------------------------------------- QKV weight fold (per head)
__global__ __launch_bounds__(256) void prep_wqkvT(
    const float* __restrict__ Pq, const float* __restrict__ Vq, const float* __restrict__ bq,
    const float* __restrict__ Pk, const float* __restrict__ Vk, const float* __restrict__ bk,
    const float* __restrict__ Pv, const float* __restrict__ Vv, const float* __restrict__ bv,
    __hip_bfloat16* __restrict__ wT, float* __restrict__ bqkv) {
  int t = blockIdx.x / NH, h = blockIdx.x % NH;
  const float* P = (t == 0) ? Pq : (t == 1) ? Pk : Pv;
  const float* V = (t == 0) ? Vq : (t == 1) ? Vk : Vv;
  const float* bb = (t == 0) ? bq : (t == 1) ? bk : bv;
  __shared__ float vs[NR][NDH];
  const int tid = threadIdx.x;
  for (int i = tid; i < NR * NDH; i += 256)
    ((float*)vs)[i] = V[(size_t)h * NR * NDH + i];
  if (tid < NDH) bqkv[t * NDM + h * NDH + tid] = bb[h * NDH + tid];
  __syncthreads();
  for (int it = 0; it < 12; it++) {
    int slot = it * 256 + tid;
    int dm = slot >> 2, qd = slot & 3;
    const float4* prow = (const float4*)(P + ((size_t)h * NDM + dm) * NR);
    float4 p4[8];
#pragma unroll
    for (int c = 0; c < 8; c++) p4[c] = prow[c];
    f32x4 a0 = {0, 0, 0, 0}, a1 = {0, 0, 0, 0}, a2 = {0, 0, 0, 0}, a3 = {0, 0, 0, 0};
#pragma unroll
    for (int r = 0; r < NR; r++) {
      float pv;
      {
        float4 pc = p4[r >> 2];
        pv = (r & 3) == 0 ? pc.x : (r & 3) == 1 ? pc.y : (r & 3) == 2 ? pc.z : pc.w;
      }
      const f32x4* vr = (const f32x4*)&vs[r][qd * 16];
      a0 += pv * vr[0];
      a1 += pv * vr[1];
      a2 += pv * vr[2];
      a3 += pv * vr[3];
    }
    int nb = t * NDM + h * NDH + qd * 16;
#pragma unroll
    for (int d = 0; d < 4; d++) {
      wT[(size_t)(nb + d) * NDM + dm] = __float2bfloat16(a0[d]);
      wT[(size_t)(nb + 4 + d) * NDM + dm] = __float2bfloat16(a1[d]);
      wT[(size_t)(nb + 8 + d) * NDM + dm] = __float2bfloat16(a2[d]);
      wT[(size_t)(nb + 12 + d) * NDM + dm] = __float2bfloat16(a3[d]);
    }
  }
}

// ---------------------------------------------------------------- GEMM (bf16)
// C[M][N] = A[M][K] @ Bt[N][K]^T, 128xBNt tile, BK=64, 4 waves.
// EPI: 0 ->bf16 ; 1 +bias ->bf16 ; 2 gelu(+bias) ->bf16 ; 3 +bias+f32resid ->f32
//      4 QKV split ; 5 +bias+bf16resid ->f32
template <int EPI, int BNt>
__global__ __launch_bounds__(256) void gemm_bt(
    const __hip_bfloat16* __restrict__ A, const __hip_bfloat16* __restrict__ Bt,
    int M, int N, int K,
    const float* __restrict__ bias, const float* __restrict__ resid,
    const __hip_bfloat16* __restrict__ residb,
    __hip_bfloat16* __restrict__ outb, float* __restrict__ outf,
    __hip_bfloat16* __restrict__ vtout) {
  constexpr int NWC = BNt / 64;         // waves along N
  constexpr int NWR = 4 / NWC;          // waves along M
  constexpr int IFR = 128 / (NWR * 16); // i-frags per wave
  constexpr int WROWS = 128 / NWR;
  constexpr int BCH = BNt / 32;         // per-wave B chunks (8 rows each)
  __shared__ __align__(16) char lsA[128 * 128];
  __shared__ __align__(16) char lsB[BNt * 128];
  const int tid = threadIdx.x;
  const int lane = tid & 63, wid = tid >> 6;
  const int wr = wid / NWC, wc = wid % NWC;
  const int gx = gridDim.x;
  const int wg = xcd_swizzle(blockIdx.y * gx + blockIdx.x, gx * gridDim.y);
  const int bm = (wg / gx) * 128, bn = (wg % gx) * BNt;
  const int g = lane >> 4, q = lane & 15;

  const int l3 = lane >> 3;
  const int kc = (lane & 7) ^ l3;

  f32x4 acc[IFR][4];
#pragma unroll
  for (int i = 0; i < IFR; i++)
#pragma unroll
    for (int j = 0; j < 4; j++) acc[i][j] = f32x4{0.f, 0.f, 0.f, 0.f};

  for (int k0 = 0; k0 < K; k0 += 64) {
#pragma unroll
    for (int c = 0; c < 4; c++) {
      int chunk = wid * 4 + c;
      int row = chunk * 8 + l3;
      const __hip_bfloat16* ga = A + (size_t)(bm + row) * K + k0 + kc * 8;
      __builtin_amdgcn_global_load_lds(
          (const __attribute__((address_space(1))) void*)ga,
          (__attribute__((address_space(3))) void*)&lsA[chunk * 1024], 16, 0, 0);
    }
#pragma unroll
    for (int c = 0; c < BCH; c++) {
      int chunk = wid * BCH + c;
      int row = chunk * 8 + l3;
      const __hip_bfloat16* gb = Bt + (size_t)(bn + row) * K + k0 + kc * 8;
      __builtin_amdgcn_global_load_lds(
          (const __attribute__((address_space(1))) void*)gb,
          (__attribute__((address_space(3))) void*)&lsB[chunk * 1024], 16, 0, 0);
    }
    __syncthreads();
#pragma unroll
    for (int ks = 0; ks < 2; ks++) {
      bf16x8 af[IFR], bfr[4];
#pragma unroll
      for (int i = 0; i < IFR; i++) {
        int ra = wr * WROWS + i * 16 + q;
        af[i] = *(const bf16x8*)&lsA[ra * 128 + ((ks * 64 + g * 16) ^ ((ra & 7) << 4))];
      }
#pragma unroll
      for (int j = 0; j < 4; j++) {
        int rb = wc * 64 + j * 16 + q;
        bfr[j] = *(const bf16x8*)&lsB[rb * 128 + ((ks * 64 + g * 16) ^ ((rb & 7) << 4))];
      }
      __builtin_amdgcn_s_setprio(1);
#pragma unroll
      for (int i = 0; i < IFR; i++)
#pragma unroll
        for (int j = 0; j < 4; j++)
          acc[i][j] = __builtin_amdgcn_mfma_f32_16x16x32_bf16(af[i], bfr[j], acc[i][j], 0, 0, 0);
      __builtin_amdgcn_s_setprio(0);
    }
    __syncthreads();
  }

  if (EPI == 4 && bn >= NQK) {
#pragma unroll
    for (int i = 0; i < IFR; i++)
#pragma unroll
      for (int j = 0; j < 4; j++) {
        int col = bn + wc * 64 + j * 16 + q;
        int cv = col - NQK;
        int h = cv >> 6, dh = cv & 63;
        int row0 = bm + wr * WROWS + i * 16 + g * 4;
        int b = row0 >> 10, m0 = row0 & 1023;
        float bi = bias[col];
        ushort4 st = {f2bf(acc[i][j][0] + bi), f2bf(acc[i][j][1] + bi),
                      f2bf(acc[i][j][2] + bi), f2bf(acc[i][j][3] + bi)};
        *(ushort4*)&vtout[(((size_t)b * NH + h) * NDH + dh) * NM + m0] = st;
      }
    return;
  }

#pragma unroll
  for (int i = 0; i < IFR; i++)
#pragma unroll
    for (int j = 0; j < 4; j++)
#pragma unroll
      for (int e = 0; e < 4; e++) {
        int row = bm + wr * WROWS + i * 16 + g * 4 + e;
        int col = bn + wc * 64 + j * 16 + q;
        float v = acc[i][j][e];
        if (EPI >= 1) v += bias[col];
        if (EPI == 2) v = 0.5f * v * (1.0f + erff(v * 0.70710678118654752f));
        if (EPI == 3) {
          v += resid[(size_t)row * N + col];
          outf[(size_t)row * N + col] = v;
        } else if (EPI == 5) {
          v += __bfloat162float(residb[(size_t)row * N + col]);
          outf[(size_t)row * N + col] = v;
        } else if (EPI == 4) {
          outb[(size_t)row * NQK + col] = __float2bfloat16(v);
        } else {
          outb[(size_t)row * N + col] = __float2bfloat16(v);
        }
      }
}

// ------------------------------------------------------------- flash attention
__global__ __launch_bounds__(256) void attn_kernel(const __hip_bfloat16* __restrict__ qk,
                                                   const __hip_bfloat16* __restrict__ vt,
                                                   const float* __restrict__ mask2,
                                                   __hip_bfloat16* __restrict__ attnb) {
  __shared__ __align__(16) char Kl[2][64 * 128];
  __shared__ __align__(16) char Vl[2][64 * 128];   // row = dh, col = n
  __shared__ __align__(16) char Pl[4][16 * 128];   // row = m(16), col = kv
  const int nblk = NB * NH * (NM / 64);
  const int blk = xcd_swizzle(blockIdx.x, nblk);
  const int qb = blk & 15;
  const int h = (blk >> 4) % NH;
  const int b = blk / (16 * NH);
  const int tid = threadIdx.x;
  const int lane = tid & 63, w = tid >> 6;
  const int g = lane >> 4, q = lane & 15;
  const size_t rowbase = (size_t)b * NM;
  const float S2 = 0.125f * 1.44269504088896f;

  const __hip_bfloat16* Kbase = qk + rowbase * NQK + NDM + h * 64;
  const __hip_bfloat16* Vbase = vt + ((size_t)(b * NH + h) * NDH) * NM;

  bf16x8 qf[2];
#pragma unroll
  for (int ks = 0; ks < 2; ks++)
    qf[ks] = *(const bf16x8*)(qk + (rowbase + qb * 64 + w * 16 + q) * NQK + h * 64 + g * 8 + ks * 32);

  const int l3 = lane >> 3;
  const int kc = (lane & 7) ^ l3;

  auto stage = [&](int buf, int t) {
    const int kv0 = t * 64;
#pragma unroll
    for (int c = 0; c < 2; c++) {
      int r8 = w * 16 + c * 8;
      int row = r8 + l3;
      const __hip_bfloat16* gk = Kbase + (size_t)(kv0 + row) * NQK + kc * 8;
      __builtin_amdgcn_global_load_lds(
          (const __attribute__((address_space(1))) void*)gk,
          (__attribute__((address_space(3))) void*)&Kl[buf][r8 * 128], 16, 0, 0);
      const __hip_bfloat16* gv = Vbase + (size_t)row * NM + kv0 + kc * 8;
      __builtin_amdgcn_global_load_lds(
          (const __attribute__((address_space(1))) void*)gv,
          (__attribute__((address_space(3))) void*)&Vl[buf][r8 * 128], 16, 0, 0);
    }
  };

  f32x4 oacc[4];
#pragma unroll
  for (int dt = 0; dt < 4; dt++) oacc[dt] = f32x4{0.f, 0.f, 0.f, 0.f};
  float mrun = -1e30f, lrun = 0.f;

  stage(0, 0);
  __syncthreads();

  for (int t = 0; t < NM / 64; t++) {
    const int cur = t & 1;
    if (t + 1 < NM / 64) stage(cur ^ 1, t + 1);
    const int kv0 = t * 64;

    f32x4 sacc[4];
#pragma unroll
    for (int nt = 0; nt < 4; nt++) sacc[nt] = f32x4{0.f, 0.f, 0.f, 0.f};
    __builtin_amdgcn_s_setprio(1);
#pragma unroll
    for (int ks = 0; ks < 2; ks++) {
#pragma unroll
      for (int nt = 0; nt < 4; nt++) {
        int r = nt * 16 + q;
        bf16x8 kf = *(const bf16x8*)&Kl[cur][r * 128 + ((ks * 64 + g * 16) ^ ((r & 7) << 4))];
        sacc[nt] = __builtin_amdgcn_mfma_f32_16x16x32_bf16(kf, qf[ks], sacc[nt], 0, 0, 0);
      }
    }
    __builtin_amdgcn_s_setprio(0);

    float zs[4][4];
    float mx = -1e30f;
#pragma unroll
    for (int nt = 0; nt < 4; nt++) {
      const float4 mk = *(const float4*)(mask2 + b * NM + kv0 + nt * 16 + g * 4);
      zs[nt][0] = fmaf(sacc[nt][0], S2, mk.x);
      zs[nt][1] = fmaf(sacc[nt][1], S2, mk.y);
      zs[nt][2] = fmaf(sacc[nt][2], S2, mk.z);
      zs[nt][3] = fmaf(sacc[nt][3], S2, mk.w);
#pragma unroll
      for (int e = 0; e < 4; e++) mx = fmaxf(mx, zs[nt][e]);
    }
    mx = fmaxf(mx, __shfl_xor(mx, 16));
    mx = fmaxf(mx, __shfl_xor(mx, 32));

    // defer-max (T13): skip O-rescale when max growth <= 11.5 (log2 units)
    if (!__all(mx - mrun <= 11.5f)) {
      float mnew = fmaxf(mrun, mx);
      float corr = fexp2(mrun - mnew);
      mrun = mnew;
      lrun *= corr;
      float corrm[4];
#pragma unroll
      for (int e = 0; e < 4; e++) corrm[e] = __shfl(corr, g * 4 + e);
#pragma unroll
      for (int dt = 0; dt < 4; dt++)
#pragma unroll
        for (int e = 0; e < 4; e++) oacc[dt][e] *= corrm[e];
    }

    float rsum = 0.f;
    float p[4][4];
#pragma unroll
    for (int nt = 0; nt < 4; nt++)
#pragma unroll
      for (int e = 0; e < 4; e++) {
        float pe = fexp2(zs[nt][e] - mrun);
        p[nt][e] = pe;
        rsum += pe;
      }
    rsum += __shfl_xor(rsum, 16);
    rsum += __shfl_xor(rsum, 32);
    lrun += rsum;

#pragma unroll
    for (int nt = 0; nt < 4; nt++) {
      ushort4 pk;
      pk.x = f2bf(p[nt][0]);
      pk.y = f2bf(p[nt][1]);
      pk.z = f2bf(p[nt][2]);
      pk.w = f2bf(p[nt][3]);
      *(ushort4*)&Pl[w][q * 128 + ((nt * 32 + g * 8) ^ ((q & 7) << 4))] = pk;
    }

    __builtin_amdgcn_s_setprio(1);
#pragma unroll
    for (int ks = 0; ks < 2; ks++) {
      bf16x8 pf = *(const bf16x8*)&Pl[w][q * 128 + ((ks * 64 + g * 16) ^ ((q & 7) << 4))];
#pragma unroll
      for (int dt = 0; dt < 4; dt++) {
        int r = dt * 16 + q;
        bf16x8 vf = *(const bf16x8*)&Vl[cur][r * 128 + ((ks * 64 + g * 16) ^ ((r & 7) << 4))];
        oacc[dt] = __builtin_amdgcn_mfma_f32_16x16x32_bf16(pf, vf, oacc[dt], 0, 0, 0);
      }
    }
    __builtin_amdgcn_s_setprio(0);
    __syncthreads();
  }

  float lm[4];
#pragma unroll
  for (int e = 0; e < 4; e++) lm[e] = 1.0f / __shfl(lrun, g * 4 + e);
#pragma unroll
  for (int dt = 0; dt < 4; dt++)
#pragma unroll
    for (int e = 0; e < 4; e++) {
      int m = qb * 64 + w * 16 + g * 4 + e;
      int dh = dt * 16 + q;
      attnb[(rowbase + m) * NDM + h * 64 + dh] = __float2bfloat16(oacc[dt][e] * lm[e]);
    }
}

// ------------------------------------------------------------------- layernorm
__global__ __launch_bounds__(256) void ln_kernel(const float* __restrict__ in, const float* __restrict__ gam,
                                                 const float* __restrict__ bet, float* __restrict__ outf,
                                                 __hip_bfloat16* __restrict__ outb) {
  const int row = blockIdx.x, tid = threadIdx.x;
  const float* p = in + (size_t)row * NDM;
  float v0 = p[tid], v1 = p[tid + 256], v2 = p[tid + 512];
  float s = v0 + v1 + v2, s2 = v0 * v0 + v1 * v1 + v2 * v2;
#pragma unroll
  for (int d = 1; d < 64; d <<= 1) {
    s += __shfl_xor(s, d);
    s2 += __shfl_xor(s2, d);
  }
  __shared__ float red[8];
  int w = tid >> 6;
  if ((tid & 63) == 0) { red[w] = s; red[4 + w] = s2; }
  __syncthreads();
  s = red[0] + red[1] + red[2] + red[3];
  s2 = red[4] + red[5] + red[6] + red[7];
  float mu = s * (1.0f / NDM);
  float var = fmaxf(s2 * (1.0f / NDM) - mu * mu, 0.0f);
  float rr = rsqrtf(var + 1e-12f);
  float o0 = (v0 - mu) * rr * gam[tid] + bet[tid];
  float o1 = (v1 - mu) * rr * gam[tid + 256] + bet[tid + 256];
  float o2 = (v2 - mu) * rr * gam[tid + 512] + bet[tid + 512];
  if (outf) {
    float* po = outf + (size_t)row * NDM;
    po[tid] = o0;
    po[tid + 256] = o1;
    po[tid + 512] = o2;
  }
  if (outb) {
    __hip_bfloat16* pb = outb + (size_t)row * NDM;
    pb[tid] = __float2bfloat16(o0);
    pb[tid + 256] = __float2bfloat16(o1);
    pb[tid + 512] = __float2bfloat16(o2);
  }
}

// ------------------------------------------------------------------- launcher
extern "C" void kernel_launch(void* const* d_in, const int* in_sizes, int n_in,
                              void* d_out, int out_size, void* d_ws, size_t ws_size,
                              hipStream_t stream) {
  const float* x = (const float*)d_in[0];
  const float* mask = (const float*)d_in[1];
  const float* Pq = (const float*)d_in[2];
  const float* Vq = (const float*)d_in[3];
  const float* bq = (const float*)d_in[4];
  const float* Pk = (const float*)d_in[5];
  const float* Vk = (const float*)d_in[6];
  const float* bk = (const float*)d_in[7];
  const float* Pv = (const float*)d_in[8];
  const float* Vv = (const float*)d_in[9];
  const float* bv = (const float*)d_in[10];
  const float* Uo = (const float*)d_in[11];
  const float* Vo = (const float*)d_in[12];
  const float* bo = (const float*)d_in[13];
  const float* U1 = (const float*)d_in[14];
  const float* V1 = (const float*)d_in[15];
  const float* b1 = (const float*)d_in[16];
  const float* U2 = (const float*)d_in[17];
  const float* V2 = (const float*)d_in[18];
  const float* b2 = (const float*)d_in[19];
  const float* ln1g = (const float*)d_in[20];
  const float* ln1b = (const float*)d_in[21];
  const float* ln2g = (const float*)d_in[22];
  const float* ln2b = (const float*)d_in[23];
  float* out = (float*)d_out;
  char* ws = (char*)d_ws;

  size_t off = 0;
  auto alloc = [&](size_t bytes) { size_t o = off; off += (bytes + 255) & ~(size_t)255; return o; };
  const size_t o_xb    = alloc((size_t)ROWS * NDM * 2);
  const size_t o_wqkvT = alloc((size_t)NQKV * NDM * 2);
  const size_t o_bqkv  = alloc((size_t)NQKV * 4);
  const size_t o_woT   = alloc((size_t)NDM * NDM * 2);
  const size_t o_uoB   = alloc((size_t)NDM * NRWO * 2);
  const size_t o_voT   = alloc((size_t)NDM * NRWO * 2);
  const size_t o_u1T   = alloc((size_t)NRFF * NDM * 2);
  const size_t o_v1T   = alloc((size_t)NDFF * NRFF * 2);
  const size_t o_u2T   = alloc((size_t)NRFF * NDFF * 2);
  const size_t o_v2T   = alloc((size_t)NDM * NRFF * 2);
  const size_t o_mask2 = alloc((size_t)NB * NM * 4);
  const size_t o_qk    = alloc((size_t)ROWS * NQK * 2);
  const size_t o_vt    = alloc((size_t)NB * NH * NDH * NM * 2);
  const size_t o_attnb = alloc((size_t)ROWS * NDM * 2);
  const size_t o_tmp   = alloc((size_t)ROWS * NDM * 4);
  const size_t o_x1b   = alloc((size_t)ROWS * NDM * 2);
  const size_t o_mid   = alloc((size_t)ROWS * NRFF * 2);
  const size_t o_mid2  = alloc((size_t)ROWS * NRFF * 2);
  const size_t o_hdn   = o_qk;  // hdn [8192][3072] bf16 over qk+vt+attnb (dead)

  __hip_bfloat16* xb    = (__hip_bfloat16*)(ws + o_xb);
  __hip_bfloat16* wqkvT = (__hip_bfloat16*)(ws + o_wqkvT);
  float*          bqkv  = (float*)(ws + o_bqkv);
  __hip_bfloat16* woT   = (__hip_bfloat16*)(ws + o_woT);
  __hip_bfloat16* uoB   = (__hip_bfloat16*)(ws + o_uoB);
  __hip_bfloat16* voT   = (__hip_bfloat16*)(ws + o_voT);
  __hip_bfloat16* u1T   = (__hip_bfloat16*)(ws + o_u1T);
  __hip_bfloat16* v1T   = (__hip_bfloat16*)(ws + o_v1T);
  __hip_bfloat16* u2T   = (__hip_bfloat16*)(ws + o_u2T);
  __hip_bfloat16* v2T   = (__hip_bfloat16*)(ws + o_v2T);
  float*          mask2 = (float*)(ws + o_mask2);
  __hip_bfloat16* qkb   = (__hip_bfloat16*)(ws + o_qk);
  __hip_bfloat16* vt    = (__hip_bfloat16*)(ws + o_vt);
  __hip_bfloat16* attnb = (__hip_bfloat16*)(ws + o_attnb);
  float*          tmp   = (float*)(ws + o_tmp);
  __hip_bfloat16* x1b   = (__hip_bfloat16*)(ws + o_x1b);
  __hip_bfloat16* mid   = (__hip_bfloat16*)(ws + o_mid);
  __hip_bfloat16* mid2  = (__hip_bfloat16*)(ws + o_mid2);
  __hip_bfloat16* hdn   = (__hip_bfloat16*)(ws + o_hdn);

  // --- prep (3 launches)
  prep_elem<<<1024, 256, 0, stream>>>(x, Uo, mask, xb, uoB, mask2);
  prep_tT<<<792, 256, 0, stream>>>(Vo, U1, V1, U2, V2, voT, u1T, v1T, u2T, v2T);
  prep_wqkvT<<<36, 256, 0, stream>>>(Pq, Vq, bq, Pk, Vk, bk, Pv, Vv, bv, wqkvT, bqkv);

  // --- WoT[n][k] = sum_r voT[n][r] * Uo[k][r]
  gemm_bt<0, 64><<<dim3(NDM / 64, NDM / 128), 256, 0, stream>>>(
      voT, uoB, NDM, NDM, NRWO, nullptr, nullptr, nullptr, woT, nullptr, nullptr);

  // --- QKV: Q/K -> qkb[8192][1536], V -> vt[b][h][dh][m]
  gemm_bt<4, 128><<<dim3(NQKV / 128, ROWS / 128), 256, 0, stream>>>(
      xb, wqkvT, ROWS, NQKV, NDM, bqkv, nullptr, nullptr, qkb, nullptr, vt);

  // --- attention
  attn_kernel<<<NB * NH * (NM / 64), 256, 0, stream>>>(qkb, vt, mask2, attnb);

  // --- Wo proj + bias + residual(x f32) -> tmp; LN1 -> x1b
  gemm_bt<3, 64><<<dim3(NDM / 64, ROWS / 128), 256, 0, stream>>>(
      attnb, woT, ROWS, NDM, NDM, bo, x, nullptr, nullptr, tmp, nullptr);
  ln_kernel<<<ROWS, 256, 0, stream>>>(tmp, ln1g, ln1b, nullptr, x1b);

  // --- FFN
  gemm_bt<0, 64><<<dim3(NRFF / 64, ROWS / 128), 256, 0, stream>>>(
      x1b, u1T, ROWS, NRFF, NDM, nullptr, nullptr, nullptr, mid, nullptr, nullptr);
  gemm_bt<2, 128><<<dim3(NDFF / 128, ROWS / 128), 256, 0, stream>>>(
      mid, v1T, ROWS, NDFF, NRFF, b1, nullptr, nullptr, hdn, nullptr, nullptr);
  gemm_bt<0, 64><<<dim3(NRFF / 64, ROWS / 128), 256, 0, stream>>>(
      hdn, u2T, ROWS, NRFF, NDFF, nullptr, nullptr, nullptr, mid2, nullptr, nullptr);
  gemm_bt<5, 64><<<dim3(NDM / 64, ROWS / 128), 256, 0, stream>>>(
      mid2, v2T, ROWS, NDM, NRFF, b2, nullptr, x1b, nullptr, tmp, nullptr);

  // --- LN2 -> out (f32)
  ln_kernel<<<ROWS, 256, 0, stream>>>(tmp, ln2g, ln2b, out, nullptr);

  (void)in_sizes; (void)n_in; (void)out_size; (void)ws_size;
}

// Round 7
// 401.154 us; speedup vs baseline: 1.5501x; 1.0959x over previous
//
#include <hip/hip_runtime.h>
#include <hip/hip_bf16.h>

// ---------------------------------------------------------------------------
// FlashSVDBlockDA: low-rank transformer block on MI355X (gfx950)
// R7: re-decomposed prep_wqkvT (R6 profile: 36 blocks / 256 VGPR / 0.03%
// occupancy -> 153us for 113 MFLOP). Now 432 blocks, 1 dm-lane per thread,
// single pass, coalesced stores. Everything else unchanged from R6.
// ---------------------------------------------------------------------------

typedef float f32x4 __attribute__((ext_vector_type(4)));
typedef __bf16 bf16x8 __attribute__((ext_vector_type(8)));

#define NB   8
#define NM   1024
#define NDM  768
#define NH   12
#define NDH  64
#define NR   32
#define NRFF 384
#define NDFF 3072
#define NRWO 384
#define ROWS (NB*NM)   // 8192
#define NQKV 2304      // 3*H*DH
#define NQK  1536      // Q+K packed row stride

__device__ __forceinline__ float fexp2(float x) {
#if __has_builtin(__builtin_amdgcn_exp2f)
  return __builtin_amdgcn_exp2f(x);
#else
  return exp2f(x);
#endif
}

__device__ __forceinline__ unsigned short f2bf(float f) {
  __hip_bfloat16 h = __float2bfloat16(f);
  return *reinterpret_cast<unsigned short*>(&h);
}

// bijective XCD swizzle
__device__ __forceinline__ int xcd_swizzle(int orig, int nwg) {
  int q = nwg >> 3, r = nwg & 7;
  int xcd = orig & 7, idx = orig >> 3;
  return (xcd < r ? xcd * (q + 1) : r * (q + 1) + (xcd - r) * q) + idx;
}

// ------------------------------------------------- elementwise prep (1 kernel)
__global__ void prep_elem(const float* __restrict__ x, const float* __restrict__ Uo,
                          const float* __restrict__ mask,
                          __hip_bfloat16* __restrict__ xb, __hip_bfloat16* __restrict__ uoB,
                          float* __restrict__ mask2) {
  const int NX = 1572864, NU = 73728, NMK = 2048;
  for (int i = blockIdx.x * blockDim.x + threadIdx.x; i < NX + NU + NMK;
       i += gridDim.x * blockDim.x) {
    if (i < NX) {
      float4 v = ((const float4*)x)[i];
      ushort4 o = {f2bf(v.x), f2bf(v.y), f2bf(v.z), f2bf(v.w)};
      ((ushort4*)xb)[i] = o;
    } else if (i < NX + NU) {
      int j = i - NX;
      float4 v = ((const float4*)Uo)[j];
      ushort4 o = {f2bf(v.x), f2bf(v.y), f2bf(v.z), f2bf(v.w)};
      ((ushort4*)uoB)[j] = o;
    } else {
      int j = i - NX - NU;
      float4 v = ((const float4*)mask)[j];
      const float L = 1.44269504088896f;
      float4 o = {v.x * L, v.y * L, v.z * L, v.w * L};
      ((float4*)mask2)[j] = o;
    }
  }
}

// ------------------------------------------------- tiled transpose-casts
__global__ __launch_bounds__(256) void prep_tT(
    const float* __restrict__ Vo, const float* __restrict__ U1, const float* __restrict__ V1,
    const float* __restrict__ U2, const float* __restrict__ V2,
    __hip_bfloat16* __restrict__ voT, __hip_bfloat16* __restrict__ u1T,
    __hip_bfloat16* __restrict__ v1T, __hip_bfloat16* __restrict__ u2T,
    __hip_bfloat16* __restrict__ v2T) {
  int blk = blockIdx.x;
  const float* src; __hip_bfloat16* dst; int R, C, lid;
  if (blk < 72)        { src = Vo; dst = voT; R = 384;  C = 768;  lid = blk; }
  else if (blk < 144)  { src = U1; dst = u1T; R = 768;  C = 384;  lid = blk - 72; }
  else if (blk < 432)  { src = V1; dst = v1T; R = 384;  C = 3072; lid = blk - 144; }
  else if (blk < 720)  { src = U2; dst = u2T; R = 3072; C = 384;  lid = blk - 432; }
  else                 { src = V2; dst = v2T; R = 384;  C = 768;  lid = blk - 720; }
  int tilesC = C >> 6;
  int tr = lid / tilesC, tc = lid - tr * tilesC;
  int r0 = tr << 6, c0 = tc << 6;
  __shared__ float sm[64][65];
  int tx = threadIdx.x & 63, ty = threadIdx.x >> 6;
#pragma unroll
  for (int k = 0; k < 16; k++) {
    int rr = ty * 16 + k;
    sm[rr][tx] = src[(size_t)(r0 + rr) * C + c0 + tx];
  }
  __syncthreads();
#pragma unroll
  for (int k = 0; k < 16; k++) {
    int cc = ty * 16 + k;
    dst[(size_t)(c0 + cc) * R + r0 + tx] = __float2bfloat16(sm[tx][cc]);
  }
}

// ------------------------------------------------- QKV weight fold
// grid = 36*12: block = ((t*NH+h), dm-chunk of 64). Thread: dm = chunk*64 +
// (tid&63), dh-group qd = tid>>6 (16 dh). Single pass, coalesced stores.
__global__ __launch_bounds__(256) void prep_wqkvT(
    const float* __restrict__ Pq, const float* __restrict__ Vq, const float* __restrict__ bq,
    const float* __restrict__ Pk, const float* __restrict__ Vk, const float* __restrict__ bk,
    const float* __restrict__ Pv, const float* __restrict__ Vv, const float* __restrict__ bv,
    __hip_bfloat16* __restrict__ wT, float* __restrict__ bqkv) {
  const int blk = blockIdx.x;
  const int th = blk / 12, chunk = blk % 12;
  const int t = th / NH, h = th % NH;
  const float* P = (t == 0) ? Pq : (t == 1) ? Pk : Pv;
  const float* V = (t == 0) ? Vq : (t == 1) ? Vk : Vv;
  const float* bb = (t == 0) ? bq : (t == 1) ? bk : bv;
  __shared__ float vs[NR][NDH];
  const int tid = threadIdx.x;
  for (int i = tid; i < NR * NDH; i += 256)
    ((float*)vs)[i] = V[(size_t)h * NR * NDH + i];
  if (chunk == 0 && tid < NDH) bqkv[t * NDM + h * NDH + tid] = bb[h * NDH + tid];
  __syncthreads();

  const int dm = chunk * 64 + (tid & 63);
  const int qd = tid >> 6;  // dh group: qd*16 .. qd*16+15
  const float4* prow = (const float4*)(P + ((size_t)h * NDM + dm) * NR);
  float4 p4[8];
#pragma unroll
  for (int c = 0; c < 8; c++) p4[c] = prow[c];
  f32x4 a0 = {0, 0, 0, 0}, a1 = {0, 0, 0, 0}, a2 = {0, 0, 0, 0}, a3 = {0, 0, 0, 0};
#pragma unroll
  for (int r = 0; r < NR; r++) {
    float4 pc = p4[r >> 2];
    float pv = (r & 3) == 0 ? pc.x : (r & 3) == 1 ? pc.y : (r & 3) == 2 ? pc.z : pc.w;
    const f32x4* vr = (const f32x4*)&vs[r][qd * 16];
    a0 += pv * vr[0];
    a1 += pv * vr[1];
    a2 += pv * vr[2];
    a3 += pv * vr[3];
  }
  const int nb = t * NDM + h * NDH + qd * 16;
#pragma unroll
  for (int d = 0; d < 4; d++) {
    wT[(size_t)(nb + d) * NDM + dm] = __float2bfloat16(a0[d]);
    wT[(size_t)(nb + 4 + d) * NDM + dm] = __float2bfloat16(a1[d]);
    wT[(size_t)(nb + 8 + d) * NDM + dm] = __float2bfloat16(a2[d]);
    wT[(size_t)(nb + 12 + d) * NDM + dm] = __float2bfloat16(a3[d]);
  }
}

// ---------------------------------------------------------------- GEMM (bf16)
// C[M][N] = A[M][K] @ Bt[N][K]^T, 128xBNt tile, BK=64, 4 waves.
// EPI: 0 ->bf16 ; 1 +bias ->bf16 ; 2 gelu(+bias) ->bf16 ; 3 +bias+f32resid ->f32
//      4 QKV split ; 5 +bias+bf16resid ->f32
template <int EPI, int BNt>
__global__ __launch_bounds__(256) void gemm_bt(
    const __hip_bfloat16* __restrict__ A, const __hip_bfloat16* __restrict__ Bt,
    int M, int N, int K,
    const float* __restrict__ bias, const float* __restrict__ resid,
    const __hip_bfloat16* __restrict__ residb,
    __hip_bfloat16* __restrict__ outb, float* __restrict__ outf,
    __hip_bfloat16* __restrict__ vtout) {
  constexpr int NWC = BNt / 64;         // waves along N
  constexpr int NWR = 4 / NWC;          // waves along M
  constexpr int IFR = 128 / (NWR * 16); // i-frags per wave
  constexpr int WROWS = 128 / NWR;
  constexpr int BCH = BNt / 32;         // per-wave B chunks (8 rows each)
  __shared__ __align__(16) char lsA[128 * 128];
  __shared__ __align__(16) char lsB[BNt * 128];
  const int tid = threadIdx.x;
  const int lane = tid & 63, wid = tid >> 6;
  const int wr = wid / NWC, wc = wid % NWC;
  const int gx = gridDim.x;
  const int wg = xcd_swizzle(blockIdx.y * gx + blockIdx.x, gx * gridDim.y);
  const int bm = (wg / gx) * 128, bn = (wg % gx) * BNt;
  const int g = lane >> 4, q = lane & 15;

  const int l3 = lane >> 3;
  const int kc = (lane & 7) ^ l3;

  f32x4 acc[IFR][4];
#pragma unroll
  for (int i = 0; i < IFR; i++)
#pragma unroll
    for (int j = 0; j < 4; j++) acc[i][j] = f32x4{0.f, 0.f, 0.f, 0.f};

  for (int k0 = 0; k0 < K; k0 += 64) {
#pragma unroll
    for (int c = 0; c < 4; c++) {
      int chunk = wid * 4 + c;
      int row = chunk * 8 + l3;
      const __hip_bfloat16* ga = A + (size_t)(bm + row) * K + k0 + kc * 8;
      __builtin_amdgcn_global_load_lds(
          (const __attribute__((address_space(1))) void*)ga,
          (__attribute__((address_space(3))) void*)&lsA[chunk * 1024], 16, 0, 0);
    }
#pragma unroll
    for (int c = 0; c < BCH; c++) {
      int chunk = wid * BCH + c;
      int row = chunk * 8 + l3;
      const __hip_bfloat16* gb = Bt + (size_t)(bn + row) * K + k0 + kc * 8;
      __builtin_amdgcn_global_load_lds(
          (const __attribute__((address_space(1))) void*)gb,
          (__attribute__((address_space(3))) void*)&lsB[chunk * 1024], 16, 0, 0);
    }
    __syncthreads();
#pragma unroll
    for (int ks = 0; ks < 2; ks++) {
      bf16x8 af[IFR], bfr[4];
#pragma unroll
      for (int i = 0; i < IFR; i++) {
        int ra = wr * WROWS + i * 16 + q;
        af[i] = *(const bf16x8*)&lsA[ra * 128 + ((ks * 64 + g * 16) ^ ((ra & 7) << 4))];
      }
#pragma unroll
      for (int j = 0; j < 4; j++) {
        int rb = wc * 64 + j * 16 + q;
        bfr[j] = *(const bf16x8*)&lsB[rb * 128 + ((ks * 64 + g * 16) ^ ((rb & 7) << 4))];
      }
      __builtin_amdgcn_s_setprio(1);
#pragma unroll
      for (int i = 0; i < IFR; i++)
#pragma unroll
        for (int j = 0; j < 4; j++)
          acc[i][j] = __builtin_amdgcn_mfma_f32_16x16x32_bf16(af[i], bfr[j], acc[i][j], 0, 0, 0);
      __builtin_amdgcn_s_setprio(0);
    }
    __syncthreads();
  }

  if (EPI == 4 && bn >= NQK) {
#pragma unroll
    for (int i = 0; i < IFR; i++)
#pragma unroll
      for (int j = 0; j < 4; j++) {
        int col = bn + wc * 64 + j * 16 + q;
        int cv = col - NQK;
        int h = cv >> 6, dh = cv & 63;
        int row0 = bm + wr * WROWS + i * 16 + g * 4;
        int b = row0 >> 10, m0 = row0 & 1023;
        float bi = bias[col];
        ushort4 st = {f2bf(acc[i][j][0] + bi), f2bf(acc[i][j][1] + bi),
                      f2bf(acc[i][j][2] + bi), f2bf(acc[i][j][3] + bi)};
        *(ushort4*)&vtout[(((size_t)b * NH + h) * NDH + dh) * NM + m0] = st;
      }
    return;
  }

#pragma unroll
  for (int i = 0; i < IFR; i++)
#pragma unroll
    for (int j = 0; j < 4; j++)
#pragma unroll
      for (int e = 0; e < 4; e++) {
        int row = bm + wr * WROWS + i * 16 + g * 4 + e;
        int col = bn + wc * 64 + j * 16 + q;
        float v = acc[i][j][e];
        if (EPI >= 1) v += bias[col];
        if (EPI == 2) v = 0.5f * v * (1.0f + erff(v * 0.70710678118654752f));
        if (EPI == 3) {
          v += resid[(size_t)row * N + col];
          outf[(size_t)row * N + col] = v;
        } else if (EPI == 5) {
          v += __bfloat162float(residb[(size_t)row * N + col]);
          outf[(size_t)row * N + col] = v;
        } else if (EPI == 4) {
          outb[(size_t)row * NQK + col] = __float2bfloat16(v);
        } else {
          outb[(size_t)row * N + col] = __float2bfloat16(v);
        }
      }
}

// ------------------------------------------------------------- flash attention
__global__ __launch_bounds__(256) void attn_kernel(const __hip_bfloat16* __restrict__ qk,
                                                   const __hip_bfloat16* __restrict__ vt,
                                                   const float* __restrict__ mask2,
                                                   __hip_bfloat16* __restrict__ attnb) {
  __shared__ __align__(16) char Kl[2][64 * 128];
  __shared__ __align__(16) char Vl[2][64 * 128];   // row = dh, col = n
  __shared__ __align__(16) char Pl[4][16 * 128];   // row = m(16), col = kv
  const int nblk = NB * NH * (NM / 64);
  const int blk = xcd_swizzle(blockIdx.x, nblk);
  const int qb = blk & 15;
  const int h = (blk >> 4) % NH;
  const int b = blk / (16 * NH);
  const int tid = threadIdx.x;
  const int lane = tid & 63, w = tid >> 6;
  const int g = lane >> 4, q = lane & 15;
  const size_t rowbase = (size_t)b * NM;
  const float S2 = 0.125f * 1.44269504088896f;

  const __hip_bfloat16* Kbase = qk + rowbase * NQK + NDM + h * 64;
  const __hip_bfloat16* Vbase = vt + ((size_t)(b * NH + h) * NDH) * NM;

  bf16x8 qf[2];
#pragma unroll
  for (int ks = 0; ks < 2; ks++)
    qf[ks] = *(const bf16x8*)(qk + (rowbase + qb * 64 + w * 16 + q) * NQK + h * 64 + g * 8 + ks * 32);

  const int l3 = lane >> 3;
  const int kc = (lane & 7) ^ l3;

  auto stage = [&](int buf, int t) {
    const int kv0 = t * 64;
#pragma unroll
    for (int c = 0; c < 2; c++) {
      int r8 = w * 16 + c * 8;
      int row = r8 + l3;
      const __hip_bfloat16* gk = Kbase + (size_t)(kv0 + row) * NQK + kc * 8;
      __builtin_amdgcn_global_load_lds(
          (const __attribute__((address_space(1))) void*)gk,
          (__attribute__((address_space(3))) void*)&Kl[buf][r8 * 128], 16, 0, 0);
      const __hip_bfloat16* gv = Vbase + (size_t)row * NM + kv0 + kc * 8;
      __builtin_amdgcn_global_load_lds(
          (const __attribute__((address_space(1))) void*)gv,
          (__attribute__((address_space(3))) void*)&Vl[buf][r8 * 128], 16, 0, 0);
    }
  };

  f32x4 oacc[4];
#pragma unroll
  for (int dt = 0; dt < 4; dt++) oacc[dt] = f32x4{0.f, 0.f, 0.f, 0.f};
  float mrun = -1e30f, lrun = 0.f;

  stage(0, 0);
  __syncthreads();

  for (int t = 0; t < NM / 64; t++) {
    const int cur = t & 1;
    if (t + 1 < NM / 64) stage(cur ^ 1, t + 1);
    const int kv0 = t * 64;

    f32x4 sacc[4];
#pragma unroll
    for (int nt = 0; nt < 4; nt++) sacc[nt] = f32x4{0.f, 0.f, 0.f, 0.f};
    __builtin_amdgcn_s_setprio(1);
#pragma unroll
    for (int ks = 0; ks < 2; ks++) {
#pragma unroll
      for (int nt = 0; nt < 4; nt++) {
        int r = nt * 16 + q;
        bf16x8 kf = *(const bf16x8*)&Kl[cur][r * 128 + ((ks * 64 + g * 16) ^ ((r & 7) << 4))];
        sacc[nt] = __builtin_amdgcn_mfma_f32_16x16x32_bf16(kf, qf[ks], sacc[nt], 0, 0, 0);
      }
    }
    __builtin_amdgcn_s_setprio(0);

    float zs[4][4];
    float mx = -1e30f;
#pragma unroll
    for (int nt = 0; nt < 4; nt++) {
      const float4 mk = *(const float4*)(mask2 + b * NM + kv0 + nt * 16 + g * 4);
      zs[nt][0] = fmaf(sacc[nt][0], S2, mk.x);
      zs[nt][1] = fmaf(sacc[nt][1], S2, mk.y);
      zs[nt][2] = fmaf(sacc[nt][2], S2, mk.z);
      zs[nt][3] = fmaf(sacc[nt][3], S2, mk.w);
#pragma unroll
      for (int e = 0; e < 4; e++) mx = fmaxf(mx, zs[nt][e]);
    }
    mx = fmaxf(mx, __shfl_xor(mx, 16));
    mx = fmaxf(mx, __shfl_xor(mx, 32));

    // defer-max (T13): skip O-rescale when max growth <= 11.5 (log2 units)
    if (!__all(mx - mrun <= 11.5f)) {
      float mnew = fmaxf(mrun, mx);
      float corr = fexp2(mrun - mnew);
      mrun = mnew;
      lrun *= corr;
      float corrm[4];
#pragma unroll
      for (int e = 0; e < 4; e++) corrm[e] = __shfl(corr, g * 4 + e);
#pragma unroll
      for (int dt = 0; dt < 4; dt++)
#pragma unroll
        for (int e = 0; e < 4; e++) oacc[dt][e] *= corrm[e];
    }

    float rsum = 0.f;
    float p[4][4];
#pragma unroll
    for (int nt = 0; nt < 4; nt++)
#pragma unroll
      for (int e = 0; e < 4; e++) {
        float pe = fexp2(zs[nt][e] - mrun);
        p[nt][e] = pe;
        rsum += pe;
      }
    rsum += __shfl_xor(rsum, 16);
    rsum += __shfl_xor(rsum, 32);
    lrun += rsum;

#pragma unroll
    for (int nt = 0; nt < 4; nt++) {
      ushort4 pk;
      pk.x = f2bf(p[nt][0]);
      pk.y = f2bf(p[nt][1]);
      pk.z = f2bf(p[nt][2]);
      pk.w = f2bf(p[nt][3]);
      *(ushort4*)&Pl[w][q * 128 + ((nt * 32 + g * 8) ^ ((q & 7) << 4))] = pk;
    }

    __builtin_amdgcn_s_setprio(1);
#pragma unroll
    for (int ks = 0; ks < 2; ks++) {
      bf16x8 pf = *(const bf16x8*)&Pl[w][q * 128 + ((ks * 64 + g * 16) ^ ((q & 7) << 4))];
#pragma unroll
      for (int dt = 0; dt < 4; dt++) {
        int r = dt * 16 + q;
        bf16x8 vf = *(const bf16x8*)&Vl[cur][r * 128 + ((ks * 64 + g * 16) ^ ((r & 7) << 4))];
        oacc[dt] = __builtin_amdgcn_mfma_f32_16x16x32_bf16(pf, vf, oacc[dt], 0, 0, 0);
      }
    }
    __builtin_amdgcn_s_setprio(0);
    __syncthreads();
  }

  float lm[4];
#pragma unroll
  for (int e = 0; e < 4; e++) lm[e] = 1.0f / __shfl(lrun, g * 4 + e);
#pragma unroll
  for (int dt = 0; dt < 4; dt++)
#pragma unroll
    for (int e = 0; e < 4; e++) {
      int m = qb * 64 + w * 16 + g * 4 + e;
      int dh = dt * 16 + q;
      attnb[(rowbase + m) * NDM + h * 64 + dh] = __float2bfloat16(oacc[dt][e] * lm[e]);
    }
}

// ------------------------------------------------------------------- layernorm
__global__ __launch_bounds__(256) void ln_kernel(const float* __restrict__ in, const float* __restrict__ gam,
                                                 const float* __restrict__ bet, float* __restrict__ outf,
                                                 __hip_bfloat16* __restrict__ outb) {
  const int row = blockIdx.x, tid = threadIdx.x;
  const float* p = in + (size_t)row * NDM;
  float v0 = p[tid], v1 = p[tid + 256], v2 = p[tid + 512];
  float s = v0 + v1 + v2, s2 = v0 * v0 + v1 * v1 + v2 * v2;
#pragma unroll
  for (int d = 1; d < 64; d <<= 1) {
    s += __shfl_xor(s, d);
    s2 += __shfl_xor(s2, d);
  }
  __shared__ float red[8];
  int w = tid >> 6;
  if ((tid & 63) == 0) { red[w] = s; red[4 + w] = s2; }
  __syncthreads();
  s = red[0] + red[1] + red[2] + red[3];
  s2 = red[4] + red[5] + red[6] + red[7];
  float mu = s * (1.0f / NDM);
  float var = fmaxf(s2 * (1.0f / NDM) - mu * mu, 0.0f);
  float rr = rsqrtf(var + 1e-12f);
  float o0 = (v0 - mu) * rr * gam[tid] + bet[tid];
  float o1 = (v1 - mu) * rr * gam[tid + 256] + bet[tid + 256];
  float o2 = (v2 - mu) * rr * gam[tid + 512] + bet[tid + 512];
  if (outf) {
    float* po = outf + (size_t)row * NDM;
    po[tid] = o0;
    po[tid + 256] = o1;
    po[tid + 512] = o2;
  }
  if (outb) {
    __hip_bfloat16* pb = outb + (size_t)row * NDM;
    pb[tid] = __float2bfloat16(o0);
    pb[tid + 256] = __float2bfloat16(o1);
    pb[tid + 512] = __float2bfloat16(o2);
  }
}

// ------------------------------------------------------------------- launcher
extern "C" void kernel_launch(void* const* d_in, const int* in_sizes, int n_in,
                              void* d_out, int out_size, void* d_ws, size_t ws_size,
                              hipStream_t stream) {
  const float* x = (const float*)d_in[0];
  const float* mask = (const float*)d_in[1];
  const float* Pq = (const float*)d_in[2];
  const float* Vq = (const float*)d_in[3];
  const float* bq = (const float*)d_in[4];
  const float* Pk = (const float*)d_in[5];
  const float* Vk = (const float*)d_in[6];
  const float* bk = (const float*)d_in[7];
  const float* Pv = (const float*)d_in[8];
  const float* Vv = (const float*)d_in[9];
  const float* bv = (const float*)d_in[10];
  const float* Uo = (const float*)d_in[11];
  const float* Vo = (const float*)d_in[12];
  const float* bo = (const float*)d_in[13];
  const float* U1 = (const float*)d_in[14];
  const float* V1 = (const float*)d_in[15];
  const float* b1 = (const float*)d_in[16];
  const float* U2 = (const float*)d_in[17];
  const float* V2 = (const float*)d_in[18];
  const float* b2 = (const float*)d_in[19];
  const float* ln1g = (const float*)d_in[20];
  const float* ln1b = (const float*)d_in[21];
  const float* ln2g = (const float*)d_in[22];
  const float* ln2b = (const float*)d_in[23];
  float* out = (float*)d_out;
  char* ws = (char*)d_ws;

  size_t off = 0;
  auto alloc = [&](size_t bytes) { size_t o = off; off += (bytes + 255) & ~(size_t)255; return o; };
  const size_t o_xb    = alloc((size_t)ROWS * NDM * 2);
  const size_t o_wqkvT = alloc((size_t)NQKV * NDM * 2);
  const size_t o_bqkv  = alloc((size_t)NQKV * 4);
  const size_t o_woT   = alloc((size_t)NDM * NDM * 2);
  const size_t o_uoB   = alloc((size_t)NDM * NRWO * 2);
  const size_t o_voT   = alloc((size_t)NDM * NRWO * 2);
  const size_t o_u1T   = alloc((size_t)NRFF * NDM * 2);
  const size_t o_v1T   = alloc((size_t)NDFF * NRFF * 2);
  const size_t o_u2T   = alloc((size_t)NRFF * NDFF * 2);
  const size_t o_v2T   = alloc((size_t)NDM * NRFF * 2);
  const size_t o_mask2 = alloc((size_t)NB * NM * 4);
  const size_t o_qk    = alloc((size_t)ROWS * NQK * 2);
  const size_t o_vt    = alloc((size_t)NB * NH * NDH * NM * 2);
  const size_t o_attnb = alloc((size_t)ROWS * NDM * 2);
  const size_t o_tmp   = alloc((size_t)ROWS * NDM * 4);
  const size_t o_x1b   = alloc((size_t)ROWS * NDM * 2);
  const size_t o_mid   = alloc((size_t)ROWS * NRFF * 2);
  const size_t o_mid2  = alloc((size_t)ROWS * NRFF * 2);
  const size_t o_hdn   = o_qk;  // hdn [8192][3072] bf16 over qk+vt+attnb (dead)

  __hip_bfloat16* xb    = (__hip_bfloat16*)(ws + o_xb);
  __hip_bfloat16* wqkvT = (__hip_bfloat16*)(ws + o_wqkvT);
  float*          bqkv  = (float*)(ws + o_bqkv);
  __hip_bfloat16* woT   = (__hip_bfloat16*)(ws + o_woT);
  __hip_bfloat16* uoB   = (__hip_bfloat16*)(ws + o_uoB);
  __hip_bfloat16* voT   = (__hip_bfloat16*)(ws + o_voT);
  __hip_bfloat16* u1T   = (__hip_bfloat16*)(ws + o_u1T);
  __hip_bfloat16* v1T   = (__hip_bfloat16*)(ws + o_v1T);
  __hip_bfloat16* u2T   = (__hip_bfloat16*)(ws + o_u2T);
  __hip_bfloat16* v2T   = (__hip_bfloat16*)(ws + o_v2T);
  float*          mask2 = (float*)(ws + o_mask2);
  __hip_bfloat16* qkb   = (__hip_bfloat16*)(ws + o_qk);
  __hip_bfloat16* vt    = (__hip_bfloat16*)(ws + o_vt);
  __hip_bfloat16* attnb = (__hip_bfloat16*)(ws + o_attnb);
  float*          tmp   = (float*)(ws + o_tmp);
  __hip_bfloat16* x1b   = (__hip_bfloat16*)(ws + o_x1b);
  __hip_bfloat16* mid   = (__hip_bfloat16*)(ws + o_mid);
  __hip_bfloat16* mid2  = (__hip_bfloat16*)(ws + o_mid2);
  __hip_bfloat16* hdn   = (__hip_bfloat16*)(ws + o_hdn);

  // --- prep (3 launches)
  prep_elem<<<1024, 256, 0, stream>>>(x, Uo, mask, xb, uoB, mask2);
  prep_tT<<<792, 256, 0, stream>>>(Vo, U1, V1, U2, V2, voT, u1T, v1T, u2T, v2T);
  prep_wqkvT<<<432, 256, 0, stream>>>(Pq, Vq, bq, Pk, Vk, bk, Pv, Vv, bv, wqkvT, bqkv);

  // --- WoT[n][k] = sum_r voT[n][r] * Uo[k][r]
  gemm_bt<0, 64><<<dim3(NDM / 64, NDM / 128), 256, 0, stream>>>(
      voT, uoB, NDM, NDM, NRWO, nullptr, nullptr, nullptr, woT, nullptr, nullptr);

  // --- QKV: Q/K -> qkb[8192][1536], V -> vt[b][h][dh][m]
  gemm_bt<4, 128><<<dim3(NQKV / 128, ROWS / 128), 256, 0, stream>>>(
      xb, wqkvT, ROWS, NQKV, NDM, bqkv, nullptr, nullptr, qkb, nullptr, vt);

  // --- attention
  attn_kernel<<<NB * NH * (NM / 64), 256, 0, stream>>>(qkb, vt, mask2, attnb);

  // --- Wo proj + bias + residual(x f32) -> tmp; LN1 -> x1b
  gemm_bt<3, 64><<<dim3(NDM / 64, ROWS / 128), 256, 0, stream>>>(
      attnb, woT, ROWS, NDM, NDM, bo, x, nullptr, nullptr, tmp, nullptr);
  ln_kernel<<<ROWS, 256, 0, stream>>>(tmp, ln1g, ln1b, nullptr, x1b);

  // --- FFN
  gemm_bt<0, 64><<<dim3(NRFF / 64, ROWS / 128), 256, 0, stream>>>(
      x1b, u1T, ROWS, NRFF, NDM, nullptr, nullptr, nullptr, mid, nullptr, nullptr);
  gemm_bt<2, 128><<<dim3(NDFF / 128, ROWS / 128), 256, 0, stream>>>(
      mid, v1T, ROWS, NDFF, NRFF, b1, nullptr, nullptr, hdn, nullptr, nullptr);
  gemm_bt<0, 64><<<dim3(NRFF / 64, ROWS / 128), 256, 0, stream>>>(
      hdn, u2T, ROWS, NRFF, NDFF, nullptr, nullptr, nullptr, mid2, nullptr, nullptr);
  gemm_bt<5, 64><<<dim3(NDM / 64, ROWS / 128), 256, 0, stream>>>(
      mid2, v2T, ROWS, NDM, NRFF, b2, nullptr, x1b, nullptr, tmp, nullptr);

  // --- LN2 -> out (f32)
  ln_kernel<<<ROWS, 256, 0, stream>>>(tmp, ln2g, ln2b, out, nullptr);

  (void)in_sizes; (void)n_in; (void)out_size; (void)ws_size;
}

// Round 9
// 384.286 us; speedup vs baseline: 1.6181x; 1.0439x over previous
//
#include <hip/hip_runtime.h>
#include <hip/hip_bf16.h>

// ---------------------------------------------------------------------------
// FlashSVDBlockDA: low-rank transformer block on MI355X (gfx950)
// R9 = R8 with the ones-frag MFMA call fixed (was missing cbsz/abid/blgp ->
// compile error). attn no-max softmax + MFMA row sums; QKV via true low-rank.
// ---------------------------------------------------------------------------

typedef float f32x4 __attribute__((ext_vector_type(4)));
typedef __bf16 bf16x8 __attribute__((ext_vector_type(8)));

#define NB   8
#define NM   1024
#define NDM  768
#define NH   12
#define NDH  64
#define NR   32
#define NRFF 384
#define NDFF 3072
#define NRWO 384
#define ROWS (NB*NM)   // 8192
#define NQK  1536      // Q+K packed row stride
#define NTQ  1152      // 3*H*R

__device__ __forceinline__ float fexp2(float x) {
#if __has_builtin(__builtin_amdgcn_exp2f)
  return __builtin_amdgcn_exp2f(x);
#else
  return exp2f(x);
#endif
}

__device__ __forceinline__ unsigned short f2bf(float f) {
  __hip_bfloat16 h = __float2bfloat16(f);
  return *reinterpret_cast<unsigned short*>(&h);
}

// bijective XCD swizzle
__device__ __forceinline__ int xcd_swizzle(int orig, int nwg) {
  int q = nwg >> 3, r = nwg & 7;
  int xcd = orig & 7, idx = orig >> 3;
  return (xcd < r ? xcd * (q + 1) : r * (q + 1) + (xcd - r) * q) + idx;
}

// ------------------------------------------------- elementwise prep (1 kernel)
__global__ void prep_elem(const float* __restrict__ x, const float* __restrict__ Uo,
                          const float* __restrict__ mask,
                          __hip_bfloat16* __restrict__ xb, __hip_bfloat16* __restrict__ uoB,
                          float* __restrict__ mask2) {
  const int NX = 1572864, NU = 73728, NMK = 2048;
  for (int i = blockIdx.x * blockDim.x + threadIdx.x; i < NX + NU + NMK;
       i += gridDim.x * blockDim.x) {
    if (i < NX) {
      float4 v = ((const float4*)x)[i];
      ushort4 o = {f2bf(v.x), f2bf(v.y), f2bf(v.z), f2bf(v.w)};
      ((ushort4*)xb)[i] = o;
    } else if (i < NX + NU) {
      int j = i - NX;
      float4 v = ((const float4*)Uo)[j];
      ushort4 o = {f2bf(v.x), f2bf(v.y), f2bf(v.z), f2bf(v.w)};
      ((ushort4*)uoB)[j] = o;
    } else {
      int j = i - NX - NU;
      float4 v = ((const float4*)mask)[j];
      const float L = 1.44269504088896f;
      float4 o = {v.x * L, v.y * L, v.z * L, v.w * L};
      ((float4*)mask2)[j] = o;
    }
  }
}

// ------------------------------------------------- tiled transpose-casts
__global__ __launch_bounds__(256) void prep_tT(
    const float* __restrict__ Vo, const float* __restrict__ U1, const float* __restrict__ V1,
    const float* __restrict__ U2, const float* __restrict__ V2,
    __hip_bfloat16* __restrict__ voT, __hip_bfloat16* __restrict__ u1T,
    __hip_bfloat16* __restrict__ v1T, __hip_bfloat16* __restrict__ u2T,
    __hip_bfloat16* __restrict__ v2T) {
  int blk = blockIdx.x;
  const float* src; __hip_bfloat16* dst; int R, C, lid;
  if (blk < 72)        { src = Vo; dst = voT; R = 384;  C = 768;  lid = blk; }
  else if (blk < 144)  { src = U1; dst = u1T; R = 768;  C = 384;  lid = blk - 72; }
  else if (blk < 432)  { src = V1; dst = v1T; R = 384;  C = 3072; lid = blk - 144; }
  else if (blk < 720)  { src = U2; dst = u2T; R = 3072; C = 384;  lid = blk - 432; }
  else                 { src = V2; dst = v2T; R = 384;  C = 768;  lid = blk - 720; }
  int tilesC = C >> 6;
  int tr = lid / tilesC, tc = lid - tr * tilesC;
  int r0 = tr << 6, c0 = tc << 6;
  __shared__ float sm[64][65];
  int tx = threadIdx.x & 63, ty = threadIdx.x >> 6;
#pragma unroll
  for (int k = 0; k < 16; k++) {
    int rr = ty * 16 + k;
    sm[rr][tx] = src[(size_t)(r0 + rr) * C + c0 + tx];
  }
  __syncthreads();
#pragma unroll
  for (int k = 0; k < 16; k++) {
    int cc = ty * 16 + k;
    dst[(size_t)(c0 + cc) * R + r0 + tx] = __float2bfloat16(sm[tx][cc]);
  }
}

// ------------------------------------------------- P transpose: ptT[n][dm]
// n = t*384 + h*32 + r ; ptT[n][dm] = P_t[h][dm][r]. grid 36*12, block 256.
__global__ __launch_bounds__(256) void prep_pT(
    const float* __restrict__ Pq, const float* __restrict__ Pk, const float* __restrict__ Pv,
    __hip_bfloat16* __restrict__ ptT) {
  const int blk = blockIdx.x;
  const int th = blk / 12, chunk = blk % 12;
  const int t = th / NH, h = th % NH;
  const float* P = (t == 0) ? Pq : (t == 1) ? Pk : Pv;  // [H][768][32]
  __shared__ float sm[64][33];
  const int tid = threadIdx.x;
  {
    int dm_l = tid >> 2, r0 = (tid & 3) * 8;
    const float* src = P + ((size_t)h * NDM + chunk * 64 + dm_l) * NR + r0;
#pragma unroll
    for (int j = 0; j < 8; j++) sm[dm_l][r0 + j] = src[j];
  }
  __syncthreads();
  {
    int r = tid >> 3, dm0 = (tid & 7) * 8;
    int n = t * 384 + h * 32 + r;
    ushort4 lo, hi;
    lo.x = f2bf(sm[dm0 + 0][r]); lo.y = f2bf(sm[dm0 + 1][r]);
    lo.z = f2bf(sm[dm0 + 2][r]); lo.w = f2bf(sm[dm0 + 3][r]);
    hi.x = f2bf(sm[dm0 + 4][r]); hi.y = f2bf(sm[dm0 + 5][r]);
    hi.z = f2bf(sm[dm0 + 6][r]); hi.w = f2bf(sm[dm0 + 7][r]);
    ushort4* d = (ushort4*)(ptT + (size_t)n * NDM + chunk * 64 + dm0);
    d[0] = lo;
    d[1] = hi;
  }
}

// ---------------------------------------------------------------- GEMM (bf16)
// C[M][N] = A[M][K] @ Bt[N][K]^T, 128xBNt tile, BK=64, 4 waves.
// EPI: 0 ->bf16 ; 1 +bias ->bf16 ; 2 gelu(+bias) ->bf16 ; 5 +bias+bf16resid ->f32
template <int EPI, int BNt>
__global__ __launch_bounds__(256) void gemm_bt(
    const __hip_bfloat16* __restrict__ A, const __hip_bfloat16* __restrict__ Bt,
    int M, int N, int K,
    const float* __restrict__ bias,
    const __hip_bfloat16* __restrict__ residb,
    __hip_bfloat16* __restrict__ outb, float* __restrict__ outf) {
  constexpr int NWC = BNt / 64;
  constexpr int NWR = 4 / NWC;
  constexpr int IFR = 128 / (NWR * 16);
  constexpr int WROWS = 128 / NWR;
  constexpr int BCH = BNt / 32;
  __shared__ __align__(16) char lsA[128 * 128];
  __shared__ __align__(16) char lsB[BNt * 128];
  const int tid = threadIdx.x;
  const int lane = tid & 63, wid = tid >> 6;
  const int wr = wid / NWC, wc = wid % NWC;
  const int gx = gridDim.x;
  const int wg = xcd_swizzle(blockIdx.y * gx + blockIdx.x, gx * gridDim.y);
  const int bm = (wg / gx) * 128, bn = (wg % gx) * BNt;
  const int g = lane >> 4, q = lane & 15;

  const int l3 = lane >> 3;
  const int kc = (lane & 7) ^ l3;

  f32x4 acc[IFR][4];
#pragma unroll
  for (int i = 0; i < IFR; i++)
#pragma unroll
    for (int j = 0; j < 4; j++) acc[i][j] = f32x4{0.f, 0.f, 0.f, 0.f};

  for (int k0 = 0; k0 < K; k0 += 64) {
#pragma unroll
    for (int c = 0; c < 4; c++) {
      int chunk = wid * 4 + c;
      int row = chunk * 8 + l3;
      const __hip_bfloat16* ga = A + (size_t)(bm + row) * K + k0 + kc * 8;
      __builtin_amdgcn_global_load_lds(
          (const __attribute__((address_space(1))) void*)ga,
          (__attribute__((address_space(3))) void*)&lsA[chunk * 1024], 16, 0, 0);
    }
#pragma unroll
    for (int c = 0; c < BCH; c++) {
      int chunk = wid * BCH + c;
      int row = chunk * 8 + l3;
      const __hip_bfloat16* gb = Bt + (size_t)(bn + row) * K + k0 + kc * 8;
      __builtin_amdgcn_global_load_lds(
          (const __attribute__((address_space(1))) void*)gb,
          (__attribute__((address_space(3))) void*)&lsB[chunk * 1024], 16, 0, 0);
    }
    __syncthreads();
#pragma unroll
    for (int ks = 0; ks < 2; ks++) {
      bf16x8 af[IFR], bfr[4];
#pragma unroll
      for (int i = 0; i < IFR; i++) {
        int ra = wr * WROWS + i * 16 + q;
        af[i] = *(const bf16x8*)&lsA[ra * 128 + ((ks * 64 + g * 16) ^ ((ra & 7) << 4))];
      }
#pragma unroll
      for (int j = 0; j < 4; j++) {
        int rb = wc * 64 + j * 16 + q;
        bfr[j] = *(const bf16x8*)&lsB[rb * 128 + ((ks * 64 + g * 16) ^ ((rb & 7) << 4))];
      }
      __builtin_amdgcn_s_setprio(1);
#pragma unroll
      for (int i = 0; i < IFR; i++)
#pragma unroll
        for (int j = 0; j < 4; j++)
          acc[i][j] = __builtin_amdgcn_mfma_f32_16x16x32_bf16(af[i], bfr[j], acc[i][j], 0, 0, 0);
      __builtin_amdgcn_s_setprio(0);
    }
    __syncthreads();
  }

#pragma unroll
  for (int i = 0; i < IFR; i++)
#pragma unroll
    for (int j = 0; j < 4; j++)
#pragma unroll
      for (int e = 0; e < 4; e++) {
        int row = bm + wr * WROWS + i * 16 + g * 4 + e;
        int col = bn + wc * 64 + j * 16 + q;
        float v = acc[i][j][e];
        if (EPI >= 1) v += bias[col];
        if (EPI == 2) v = 0.5f * v * (1.0f + erff(v * 0.70710678118654752f));
        if (EPI == 5) {
          v += __bfloat162float(residb[(size_t)row * N + col]);
          outf[(size_t)row * N + col] = v;
        } else {
          outb[(size_t)row * N + col] = __float2bfloat16(v);
        }
      }
}

// ------------------------------------------------- QKV apply: K=32 per head
// grid dim3(36, ROWS/256). out = tq[:, t*384+h*32 : +32] @ V_t[h] + b_t[h]
// t<2 -> qkb[row][t*768+h*64+dh] ; t=2 -> vt[b][h][dh][m]
__global__ __launch_bounds__(256) void qkv_apply(
    const __hip_bfloat16* __restrict__ tq,
    const float* __restrict__ Vq, const float* __restrict__ bq,
    const float* __restrict__ Vk, const float* __restrict__ bk,
    const float* __restrict__ Vv, const float* __restrict__ bv,
    __hip_bfloat16* __restrict__ qkb, __hip_bfloat16* __restrict__ vt) {
  const int th = blockIdx.x;
  const int t = th / NH, h = th % NH;
  const int bm = blockIdx.y * 256;
  const float* V = (t == 0) ? Vq : (t == 1) ? Vk : Vv;   // [H][R][DH]
  const float* bb = (t == 0) ? bq : (t == 1) ? bk : bv;  // [H][DH]
  __shared__ __align__(16) __hip_bfloat16 Vl[NDH][NR];   // [dh][r]
  const int tid = threadIdx.x;
  const int lane = tid & 63, w = tid >> 6;
  const int g = lane >> 4, q = lane & 15;

  {  // stage V transposed into LDS
    int r = tid >> 3, dh0 = (tid & 7) * 8;
    const float* src = V + ((size_t)h * NR + r) * NDH + dh0;
#pragma unroll
    for (int j = 0; j < 8; j++) Vl[dh0 + j][r] = __float2bfloat16(src[j]);
  }
  __syncthreads();

  bf16x8 bfr[4];
  float bj[4];
#pragma unroll
  for (int j = 0; j < 4; j++) {
    bfr[j] = *(const bf16x8*)&Vl[j * 16 + q][g * 8];
    bj[j] = bb[h * NDH + j * 16 + q];
  }

  bf16x8 af[4];
#pragma unroll
  for (int i = 0; i < 4; i++) {
    int row = bm + w * 64 + i * 16 + q;
    af[i] = *(const bf16x8*)(tq + (size_t)row * NTQ + t * 384 + h * 32 + g * 8);
  }

  f32x4 acc[4][4];
#pragma unroll
  for (int i = 0; i < 4; i++)
#pragma unroll
    for (int j = 0; j < 4; j++) {
      acc[i][j] = f32x4{0.f, 0.f, 0.f, 0.f};
      acc[i][j] = __builtin_amdgcn_mfma_f32_16x16x32_bf16(af[i], bfr[j], acc[i][j], 0, 0, 0);
    }

  if (t < 2) {
#pragma unroll
    for (int i = 0; i < 4; i++)
#pragma unroll
      for (int j = 0; j < 4; j++) {
        int dh = j * 16 + q;
#pragma unroll
        for (int e = 0; e < 4; e++) {
          int row = bm + w * 64 + i * 16 + g * 4 + e;
          qkb[(size_t)row * NQK + t * NDM + h * NDH + dh] = __float2bfloat16(acc[i][j][e] + bj[j]);
        }
      }
  } else {
#pragma unroll
    for (int i = 0; i < 4; i++)
#pragma unroll
      for (int j = 0; j < 4; j++) {
        int dh = j * 16 + q;
        int row0 = bm + w * 64 + i * 16 + g * 4;
        int b = row0 >> 10, m0 = row0 & 1023;
        float bi = bj[j];
        ushort4 st = {f2bf(acc[i][j][0] + bi), f2bf(acc[i][j][1] + bi),
                      f2bf(acc[i][j][2] + bi), f2bf(acc[i][j][3] + bi)};
        *(ushort4*)&vt[(((size_t)b * NH + h) * NDH + dh) * NM + m0] = st;
      }
  }
}

// ------------------------------------------------------------- flash attention
// No-max softmax (logits bounded by construction): p = exp2(S*scale + mask),
// row sums via MFMA ones-frag (lane-local, D-layout).
__global__ __launch_bounds__(256) void attn_kernel(const __hip_bfloat16* __restrict__ qk,
                                                   const __hip_bfloat16* __restrict__ vt,
                                                   const float* __restrict__ mask2,
                                                   __hip_bfloat16* __restrict__ attnb) {
  __shared__ __align__(16) char Kl[2][64 * 128];
  __shared__ __align__(16) char Vl[2][64 * 128];   // row = dh, col = n
  __shared__ __align__(16) char Pl[4][16 * 128];   // row = m(16), col = kv
  const int nblk = NB * NH * (NM / 64);
  const int blk = xcd_swizzle(blockIdx.x, nblk);
  const int qb = blk & 15;
  const int h = (blk >> 4) % NH;
  const int b = blk / (16 * NH);
  const int tid = threadIdx.x;
  const int lane = tid & 63, w = tid >> 6;
  const int g = lane >> 4, q = lane & 15;
  const size_t rowbase = (size_t)b * NM;
  const float S2 = 0.125f * 1.44269504088896f;

  const __hip_bfloat16* Kbase = qk + rowbase * NQK + NDM + h * 64;
  const __hip_bfloat16* Vbase = vt + ((size_t)(b * NH + h) * NDH) * NM;

  bf16x8 qf[2];
#pragma unroll
  for (int ks = 0; ks < 2; ks++)
    qf[ks] = *(const bf16x8*)(qk + (rowbase + qb * 64 + w * 16 + q) * NQK + h * 64 + g * 8 + ks * 32);

  bf16x8 onesf;
#pragma unroll
  for (int jj = 0; jj < 8; jj++) onesf[jj] = (__bf16)1.0f;

  const int l3 = lane >> 3;
  const int kc = (lane & 7) ^ l3;

  auto stage = [&](int buf, int t) {
    const int kv0 = t * 64;
#pragma unroll
    for (int c = 0; c < 2; c++) {
      int r8 = w * 16 + c * 8;
      int row = r8 + l3;
      const __hip_bfloat16* gk = Kbase + (size_t)(kv0 + row) * NQK + kc * 8;
      __builtin_amdgcn_global_load_lds(
          (const __attribute__((address_space(1))) void*)gk,
          (__attribute__((address_space(3))) void*)&Kl[buf][r8 * 128], 16, 0, 0);
      const __hip_bfloat16* gv = Vbase + (size_t)row * NM + kv0 + kc * 8;
      __builtin_amdgcn_global_load_lds(
          (const __attribute__((address_space(1))) void*)gv,
          (__attribute__((address_space(3))) void*)&Vl[buf][r8 * 128], 16, 0, 0);
    }
  };

  f32x4 oacc[4];
#pragma unroll
  for (int dt = 0; dt < 4; dt++) oacc[dt] = f32x4{0.f, 0.f, 0.f, 0.f};
  f32x4 lacc = f32x4{0.f, 0.f, 0.f, 0.f};

  stage(0, 0);
  __syncthreads();

  for (int t = 0; t < NM / 64; t++) {
    const int cur = t & 1;
    if (t + 1 < NM / 64) stage(cur ^ 1, t + 1);
    const int kv0 = t * 64;

    f32x4 sacc[4];
#pragma unroll
    for (int nt = 0; nt < 4; nt++) sacc[nt] = f32x4{0.f, 0.f, 0.f, 0.f};
    __builtin_amdgcn_s_setprio(1);
#pragma unroll
    for (int ks = 0; ks < 2; ks++) {
#pragma unroll
      for (int nt = 0; nt < 4; nt++) {
        int r = nt * 16 + q;
        bf16x8 kf = *(const bf16x8*)&Kl[cur][r * 128 + ((ks * 64 + g * 16) ^ ((r & 7) << 4))];
        sacc[nt] = __builtin_amdgcn_mfma_f32_16x16x32_bf16(kf, qf[ks], sacc[nt], 0, 0, 0);
      }
    }
    __builtin_amdgcn_s_setprio(0);

    // p = exp2(S*scale*log2e + mask*log2e), no max subtraction
#pragma unroll
    for (int nt = 0; nt < 4; nt++) {
      const float4 mk = *(const float4*)(mask2 + b * NM + kv0 + nt * 16 + g * 4);
      ushort4 pk;
      pk.x = f2bf(fexp2(fmaf(sacc[nt][0], S2, mk.x)));
      pk.y = f2bf(fexp2(fmaf(sacc[nt][1], S2, mk.y)));
      pk.z = f2bf(fexp2(fmaf(sacc[nt][2], S2, mk.z)));
      pk.w = f2bf(fexp2(fmaf(sacc[nt][3], S2, mk.w)));
      *(ushort4*)&Pl[w][q * 128 + ((nt * 32 + g * 8) ^ ((q & 7) << 4))] = pk;
    }

    __builtin_amdgcn_s_setprio(1);
#pragma unroll
    for (int ks = 0; ks < 2; ks++) {
      bf16x8 pf = *(const bf16x8*)&Pl[w][q * 128 + ((ks * 64 + g * 16) ^ ((q & 7) << 4))];
#pragma unroll
      for (int dt = 0; dt < 4; dt++) {
        int r = dt * 16 + q;
        bf16x8 vf = *(const bf16x8*)&Vl[cur][r * 128 + ((ks * 64 + g * 16) ^ ((r & 7) << 4))];
        oacc[dt] = __builtin_amdgcn_mfma_f32_16x16x32_bf16(pf, vf, oacc[dt], 0, 0, 0);
      }
      lacc = __builtin_amdgcn_mfma_f32_16x16x32_bf16(pf, onesf, lacc, 0, 0, 0);
    }
    __builtin_amdgcn_s_setprio(0);
    __syncthreads();
  }

  float inv[4];
#pragma unroll
  for (int e = 0; e < 4; e++) inv[e] = 1.0f / lacc[e];
#pragma unroll
  for (int dt = 0; dt < 4; dt++)
#pragma unroll
    for (int e = 0; e < 4; e++) {
      int m = qb * 64 + w * 16 + g * 4 + e;
      int dh = dt * 16 + q;
      attnb[(rowbase + m) * NDM + h * 64 + dh] = __float2bfloat16(oacc[dt][e] * inv[e]);
    }
}

// ------------------------------------------------------------------- layernorm
__global__ __launch_bounds__(256) void ln_kernel(const float* __restrict__ in, const float* __restrict__ gam,
                                                 const float* __restrict__ bet, float* __restrict__ outf,
                                                 __hip_bfloat16* __restrict__ outb) {
  const int row = blockIdx.x, tid = threadIdx.x;
  const float* p = in + (size_t)row * NDM;
  float v0 = p[tid], v1 = p[tid + 256], v2 = p[tid + 512];
  float s = v0 + v1 + v2, s2 = v0 * v0 + v1 * v1 + v2 * v2;
#pragma unroll
  for (int d = 1; d < 64; d <<= 1) {
    s += __shfl_xor(s, d);
    s2 += __shfl_xor(s2, d);
  }
  __shared__ float red[8];
  int w = tid >> 6;
  if ((tid & 63) == 0) { red[w] = s; red[4 + w] = s2; }
  __syncthreads();
  s = red[0] + red[1] + red[2] + red[3];
  s2 = red[4] + red[5] + red[6] + red[7];
  float mu = s * (1.0f / NDM);
  float var = fmaxf(s2 * (1.0f / NDM) - mu * mu, 0.0f);
  float rr = rsqrtf(var + 1e-12f);
  float o0 = (v0 - mu) * rr * gam[tid] + bet[tid];
  float o1 = (v1 - mu) * rr * gam[tid + 256] + bet[tid + 256];
  float o2 = (v2 - mu) * rr * gam[tid + 512] + bet[tid + 512];
  if (outf) {
    float* po = outf + (size_t)row * NDM;
    po[tid] = o0;
    po[tid + 256] = o1;
    po[tid + 512] = o2;
  }
  if (outb) {
    __hip_bfloat16* pb = outb + (size_t)row * NDM;
    pb[tid] = __float2bfloat16(o0);
    pb[tid + 256] = __float2bfloat16(o1);
    pb[tid + 512] = __float2bfloat16(o2);
  }
}

// ------------------------------------------------------------------- launcher
extern "C" void kernel_launch(void* const* d_in, const int* in_sizes, int n_in,
                              void* d_out, int out_size, void* d_ws, size_t ws_size,
                              hipStream_t stream) {
  const float* x = (const float*)d_in[0];
  const float* mask = (const float*)d_in[1];
  const float* Pq = (const float*)d_in[2];
  const float* Vq = (const float*)d_in[3];
  const float* bq = (const float*)d_in[4];
  const float* Pk = (const float*)d_in[5];
  const float* Vk = (const float*)d_in[6];
  const float* bk = (const float*)d_in[7];
  const float* Pv = (const float*)d_in[8];
  const float* Vv = (const float*)d_in[9];
  const float* bv = (const float*)d_in[10];
  const float* Uo = (const float*)d_in[11];
  const float* Vo = (const float*)d_in[12];
  const float* bo = (const float*)d_in[13];
  const float* U1 = (const float*)d_in[14];
  const float* V1 = (const float*)d_in[15];
  const float* b1 = (const float*)d_in[16];
  const float* U2 = (const float*)d_in[17];
  const float* V2 = (const float*)d_in[18];
  const float* b2 = (const float*)d_in[19];
  const float* ln1g = (const float*)d_in[20];
  const float* ln1b = (const float*)d_in[21];
  const float* ln2g = (const float*)d_in[22];
  const float* ln2b = (const float*)d_in[23];
  float* out = (float*)d_out;
  char* ws = (char*)d_ws;

  size_t off = 0;
  auto alloc = [&](size_t bytes) { size_t o = off; off += (bytes + 255) & ~(size_t)255; return o; };
  const size_t o_xb    = alloc((size_t)ROWS * NDM * 2);
  const size_t o_woT   = alloc((size_t)NDM * NDM * 2);
  const size_t o_uoB   = alloc((size_t)NDM * NRWO * 2);
  const size_t o_voT   = alloc((size_t)NDM * NRWO * 2);
  const size_t o_u1T   = alloc((size_t)NRFF * NDM * 2);
  const size_t o_v1T   = alloc((size_t)NDFF * NRFF * 2);
  const size_t o_u2T   = alloc((size_t)NRFF * NDFF * 2);
  const size_t o_v2T   = alloc((size_t)NDM * NRFF * 2);
  const size_t o_ptT   = alloc((size_t)NTQ * NDM * 2);
  const size_t o_mask2 = alloc((size_t)NB * NM * 4);
  const size_t o_tq    = alloc((size_t)ROWS * NTQ * 2);
  const size_t o_qk    = alloc((size_t)ROWS * NQK * 2);
  const size_t o_vt    = alloc((size_t)NB * NH * NDH * NM * 2);
  const size_t o_attnb = alloc((size_t)ROWS * NDM * 2);
  const size_t o_tmp   = alloc((size_t)ROWS * NDM * 4);
  const size_t o_x1b   = alloc((size_t)ROWS * NDM * 2);
  const size_t o_mid   = alloc((size_t)ROWS * NRFF * 2);
  const size_t o_mid2  = alloc((size_t)ROWS * NRFF * 2);
  const size_t o_hdn   = o_qk;  // hdn [8192][3072] bf16 = 50.3MB over qk+vt+attnb

  __hip_bfloat16* xb    = (__hip_bfloat16*)(ws + o_xb);
  __hip_bfloat16* woT   = (__hip_bfloat16*)(ws + o_woT);
  __hip_bfloat16* uoB   = (__hip_bfloat16*)(ws + o_uoB);
  __hip_bfloat16* voT   = (__hip_bfloat16*)(ws + o_voT);
  __hip_bfloat16* u1T   = (__hip_bfloat16*)(ws + o_u1T);
  __hip_bfloat16* v1T   = (__hip_bfloat16*)(ws + o_v1T);
  __hip_bfloat16* u2T   = (__hip_bfloat16*)(ws + o_u2T);
  __hip_bfloat16* v2T   = (__hip_bfloat16*)(ws + o_v2T);
  __hip_bfloat16* ptT   = (__hip_bfloat16*)(ws + o_ptT);
  float*          mask2 = (float*)(ws + o_mask2);
  __hip_bfloat16* tq    = (__hip_bfloat16*)(ws + o_tq);
  __hip_bfloat16* qkb   = (__hip_bfloat16*)(ws + o_qk);
  __hip_bfloat16* vt    = (__hip_bfloat16*)(ws + o_vt);
  __hip_bfloat16* attnb = (__hip_bfloat16*)(ws + o_attnb);
  float*          tmp   = (float*)(ws + o_tmp);
  __hip_bfloat16* x1b   = (__hip_bfloat16*)(ws + o_x1b);
  __hip_bfloat16* mid   = (__hip_bfloat16*)(ws + o_mid);
  __hip_bfloat16* mid2  = (__hip_bfloat16*)(ws + o_mid2);
  __hip_bfloat16* hdn   = (__hip_bfloat16*)(ws + o_hdn);

  // --- prep
  prep_elem<<<1024, 256, 0, stream>>>(x, Uo, mask, xb, uoB, mask2);
  prep_tT<<<792, 256, 0, stream>>>(Vo, U1, V1, U2, V2, voT, u1T, v1T, u2T, v2T);
  prep_pT<<<432, 256, 0, stream>>>(Pq, Pk, Pv, ptT);

  // --- WoT[n][k] = sum_r voT[n][r] * Uo[k][r]
  gemm_bt<0, 64><<<dim3(NDM / 64, NDM / 128), 256, 0, stream>>>(
      voT, uoB, NDM, NDM, NRWO, nullptr, nullptr, woT, nullptr);

  // --- tq = xb @ ptT^T   [8192][1152]
  gemm_bt<0, 128><<<dim3(NTQ / 128, ROWS / 128), 256, 0, stream>>>(
      xb, ptT, ROWS, NTQ, NDM, nullptr, nullptr, tq, nullptr);

  // --- apply V + bias: Q/K -> qkb, V -> vt
  qkv_apply<<<dim3(36, ROWS / 256), 256, 0, stream>>>(tq, Vq, bq, Vk, bk, Vv, bv, qkb, vt);

  // --- attention
  attn_kernel<<<NB * NH * (NM / 64), 256, 0, stream>>>(qkb, vt, mask2, attnb);

  // --- Wo proj + bias + residual(xb bf16) -> tmp; LN1 -> x1b
  gemm_bt<5, 64><<<dim3(NDM / 64, ROWS / 128), 256, 0, stream>>>(
      attnb, woT, ROWS, NDM, NDM, bo, xb, nullptr, tmp);
  ln_kernel<<<ROWS, 256, 0, stream>>>(tmp, ln1g, ln1b, nullptr, x1b);

  // --- FFN
  gemm_bt<0, 64><<<dim3(NRFF / 64, ROWS / 128), 256, 0, stream>>>(
      x1b, u1T, ROWS, NRFF, NDM, nullptr, nullptr, mid, nullptr);
  gemm_bt<2, 128><<<dim3(NDFF / 128, ROWS / 128), 256, 0, stream>>>(
      mid, v1T, ROWS, NDFF, NRFF, b1, nullptr, hdn, nullptr);
  gemm_bt<0, 64><<<dim3(NRFF / 64, ROWS / 128), 256, 0, stream>>>(
      hdn, u2T, ROWS, NRFF, NDFF, nullptr, nullptr, mid2, nullptr);
  gemm_bt<5, 64><<<dim3(NDM / 64, ROWS / 128), 256, 0, stream>>>(
      mid2, v2T, ROWS, NDM, NRFF, b2, x1b, nullptr, tmp);

  // --- LN2 -> out (f32)
  ln_kernel<<<ROWS, 256, 0, stream>>>(tmp, ln2g, ln2b, out, nullptr);

  (void)in_sizes; (void)n_in; (void)out_size; (void)ws_size;
}

// Round 10
// 365.775 us; speedup vs baseline: 1.7000x; 1.0506x over previous
//
#include <hip/hip_runtime.h>
#include <hip/hip_bf16.h>

// ---------------------------------------------------------------------------
// FlashSVDBlockDA: low-rank transformer block on MI355X (gfx950)
// R10: attn single-buffered K/V (LDS 40->24KB: occupancy was 29%, LDS-capped
// at 4 blk/CU vs 6 wanted; m114 inter-block overlap > intra-block prefetch),
// bf16 pre-LN buffers (EPI5 -> bf16, LN reads bf16), preps merged into one
// kernel (12 launches total).
// ---------------------------------------------------------------------------

typedef float f32x4 __attribute__((ext_vector_type(4)));
typedef __bf16 bf16x8 __attribute__((ext_vector_type(8)));

#define NB   8
#define NM   1024
#define NDM  768
#define NH   12
#define NDH  64
#define NR   32
#define NRFF 384
#define NDFF 3072
#define NRWO 384
#define ROWS (NB*NM)   // 8192
#define NQK  1536      // Q+K packed row stride
#define NTQ  1152      // 3*H*R

__device__ __forceinline__ float fexp2(float x) {
#if __has_builtin(__builtin_amdgcn_exp2f)
  return __builtin_amdgcn_exp2f(x);
#else
  return exp2f(x);
#endif
}

__device__ __forceinline__ unsigned short f2bf(float f) {
  __hip_bfloat16 h = __float2bfloat16(f);
  return *reinterpret_cast<unsigned short*>(&h);
}

// bijective XCD swizzle
__device__ __forceinline__ int xcd_swizzle(int orig, int nwg) {
  int q = nwg >> 3, r = nwg & 7;
  int xcd = orig & 7, idx = orig >> 3;
  return (xcd < r ? xcd * (q + 1) : r * (q + 1) + (xcd - r) * q) + idx;
}

// ------------------------------------------------- unified prep kernel
// blocks [0,1024): elementwise casts (x->xb, Uo->uoB, mask*log2e)
// blocks [1024,1816): tiled transpose-casts (Vo,U1,V1,U2,V2)
// blocks [1816,2248): P transpose -> ptT[n][dm]
__global__ __launch_bounds__(256) void prep_all(
    const float* __restrict__ x, const float* __restrict__ Uo, const float* __restrict__ mask,
    const float* __restrict__ Vo, const float* __restrict__ U1, const float* __restrict__ V1,
    const float* __restrict__ U2, const float* __restrict__ V2,
    const float* __restrict__ Pq, const float* __restrict__ Pk, const float* __restrict__ Pv,
    __hip_bfloat16* __restrict__ xb, __hip_bfloat16* __restrict__ uoB, float* __restrict__ mask2,
    __hip_bfloat16* __restrict__ voT, __hip_bfloat16* __restrict__ u1T,
    __hip_bfloat16* __restrict__ v1T, __hip_bfloat16* __restrict__ u2T,
    __hip_bfloat16* __restrict__ v2T, __hip_bfloat16* __restrict__ ptT) {
  const int blk = blockIdx.x;
  const int tid = threadIdx.x;
  __shared__ float sm[64][65];

  if (blk < 1024) {
    const int NX = 1572864, NU = 73728, NMK = 2048;
    for (int i = blk * 256 + tid; i < NX + NU + NMK; i += 1024 * 256) {
      if (i < NX) {
        float4 v = ((const float4*)x)[i];
        ushort4 o = {f2bf(v.x), f2bf(v.y), f2bf(v.z), f2bf(v.w)};
        ((ushort4*)xb)[i] = o;
      } else if (i < NX + NU) {
        int j = i - NX;
        float4 v = ((const float4*)Uo)[j];
        ushort4 o = {f2bf(v.x), f2bf(v.y), f2bf(v.z), f2bf(v.w)};
        ((ushort4*)uoB)[j] = o;
      } else {
        int j = i - NX - NU;
        float4 v = ((const float4*)mask)[j];
        const float L = 1.44269504088896f;
        float4 o = {v.x * L, v.y * L, v.z * L, v.w * L};
        ((float4*)mask2)[j] = o;
      }
    }
  } else if (blk < 1816) {
    int b2 = blk - 1024;
    const float* src; __hip_bfloat16* dst; int R, C, lid;
    if (b2 < 72)        { src = Vo; dst = voT; R = 384;  C = 768;  lid = b2; }
    else if (b2 < 144)  { src = U1; dst = u1T; R = 768;  C = 384;  lid = b2 - 72; }
    else if (b2 < 432)  { src = V1; dst = v1T; R = 384;  C = 3072; lid = b2 - 144; }
    else if (b2 < 720)  { src = U2; dst = u2T; R = 3072; C = 384;  lid = b2 - 432; }
    else                { src = V2; dst = v2T; R = 384;  C = 768;  lid = b2 - 720; }
    int tilesC = C >> 6;
    int tr = lid / tilesC, tc = lid - tr * tilesC;
    int r0 = tr << 6, c0 = tc << 6;
    int tx = tid & 63, ty = tid >> 6;
#pragma unroll
    for (int k = 0; k < 16; k++) {
      int rr = ty * 16 + k;
      sm[rr][tx] = src[(size_t)(r0 + rr) * C + c0 + tx];
    }
    __syncthreads();
#pragma unroll
    for (int k = 0; k < 16; k++) {
      int cc = ty * 16 + k;
      dst[(size_t)(c0 + cc) * R + r0 + tx] = __float2bfloat16(sm[tx][cc]);
    }
  } else {
    int b3 = blk - 1816;
    const int th = b3 / 12, chunk = b3 % 12;
    const int t = th / NH, h = th % NH;
    const float* P = (t == 0) ? Pq : (t == 1) ? Pk : Pv;  // [H][768][32]
    {
      int dm_l = tid >> 2, r0 = (tid & 3) * 8;
      const float* src = P + ((size_t)h * NDM + chunk * 64 + dm_l) * NR + r0;
#pragma unroll
      for (int j = 0; j < 8; j++) sm[dm_l][r0 + j] = src[j];
    }
    __syncthreads();
    {
      int r = tid >> 3, dm0 = (tid & 7) * 8;
      int n = t * 384 + h * 32 + r;
      ushort4 lo, hi;
      lo.x = f2bf(sm[dm0 + 0][r]); lo.y = f2bf(sm[dm0 + 1][r]);
      lo.z = f2bf(sm[dm0 + 2][r]); lo.w = f2bf(sm[dm0 + 3][r]);
      hi.x = f2bf(sm[dm0 + 4][r]); hi.y = f2bf(sm[dm0 + 5][r]);
      hi.z = f2bf(sm[dm0 + 6][r]); hi.w = f2bf(sm[dm0 + 7][r]);
      ushort4* d = (ushort4*)(ptT + (size_t)n * NDM + chunk * 64 + dm0);
      d[0] = lo;
      d[1] = hi;
    }
  }
}

// ---------------------------------------------------------------- GEMM (bf16)
// C[M][N] = A[M][K] @ Bt[N][K]^T, 128xBNt tile, BK=64, 4 waves.
// EPI: 0 ->bf16 ; 1 +bias ->bf16 ; 2 gelu(+bias) ->bf16 ; 5 +bias+bf16resid ->bf16
template <int EPI, int BNt>
__global__ __launch_bounds__(256) void gemm_bt(
    const __hip_bfloat16* __restrict__ A, const __hip_bfloat16* __restrict__ Bt,
    int M, int N, int K,
    const float* __restrict__ bias,
    const __hip_bfloat16* __restrict__ residb,
    __hip_bfloat16* __restrict__ outb) {
  constexpr int NWC = BNt / 64;
  constexpr int NWR = 4 / NWC;
  constexpr int IFR = 128 / (NWR * 16);
  constexpr int WROWS = 128 / NWR;
  constexpr int BCH = BNt / 32;
  __shared__ __align__(16) char lsA[128 * 128];
  __shared__ __align__(16) char lsB[BNt * 128];
  const int tid = threadIdx.x;
  const int lane = tid & 63, wid = tid >> 6;
  const int wr = wid / NWC, wc = wid % NWC;
  const int gx = gridDim.x;
  const int wg = xcd_swizzle(blockIdx.y * gx + blockIdx.x, gx * gridDim.y);
  const int bm = (wg / gx) * 128, bn = (wg % gx) * BNt;
  const int g = lane >> 4, q = lane & 15;

  const int l3 = lane >> 3;
  const int kc = (lane & 7) ^ l3;

  f32x4 acc[IFR][4];
#pragma unroll
  for (int i = 0; i < IFR; i++)
#pragma unroll
    for (int j = 0; j < 4; j++) acc[i][j] = f32x4{0.f, 0.f, 0.f, 0.f};

  for (int k0 = 0; k0 < K; k0 += 64) {
#pragma unroll
    for (int c = 0; c < 4; c++) {
      int chunk = wid * 4 + c;
      int row = chunk * 8 + l3;
      const __hip_bfloat16* ga = A + (size_t)(bm + row) * K + k0 + kc * 8;
      __builtin_amdgcn_global_load_lds(
          (const __attribute__((address_space(1))) void*)ga,
          (__attribute__((address_space(3))) void*)&lsA[chunk * 1024], 16, 0, 0);
    }
#pragma unroll
    for (int c = 0; c < BCH; c++) {
      int chunk = wid * BCH + c;
      int row = chunk * 8 + l3;
      const __hip_bfloat16* gb = Bt + (size_t)(bn + row) * K + k0 + kc * 8;
      __builtin_amdgcn_global_load_lds(
          (const __attribute__((address_space(1))) void*)gb,
          (__attribute__((address_space(3))) void*)&lsB[chunk * 1024], 16, 0, 0);
    }
    __syncthreads();
#pragma unroll
    for (int ks = 0; ks < 2; ks++) {
      bf16x8 af[IFR], bfr[4];
#pragma unroll
      for (int i = 0; i < IFR; i++) {
        int ra = wr * WROWS + i * 16 + q;
        af[i] = *(const bf16x8*)&lsA[ra * 128 + ((ks * 64 + g * 16) ^ ((ra & 7) << 4))];
      }
#pragma unroll
      for (int j = 0; j < 4; j++) {
        int rb = wc * 64 + j * 16 + q;
        bfr[j] = *(const bf16x8*)&lsB[rb * 128 + ((ks * 64 + g * 16) ^ ((rb & 7) << 4))];
      }
      __builtin_amdgcn_s_setprio(1);
#pragma unroll
      for (int i = 0; i < IFR; i++)
#pragma unroll
        for (int j = 0; j < 4; j++)
          acc[i][j] = __builtin_amdgcn_mfma_f32_16x16x32_bf16(af[i], bfr[j], acc[i][j], 0, 0, 0);
      __builtin_amdgcn_s_setprio(0);
    }
    __syncthreads();
  }

#pragma unroll
  for (int i = 0; i < IFR; i++)
#pragma unroll
    for (int j = 0; j < 4; j++)
#pragma unroll
      for (int e = 0; e < 4; e++) {
        int row = bm + wr * WROWS + i * 16 + g * 4 + e;
        int col = bn + wc * 64 + j * 16 + q;
        float v = acc[i][j][e];
        if (EPI >= 1) v += bias[col];
        if (EPI == 2) v = 0.5f * v * (1.0f + erff(v * 0.70710678118654752f));
        if (EPI == 5) v += __bfloat162float(residb[(size_t)row * N + col]);
        outb[(size_t)row * N + col] = __float2bfloat16(v);
      }
}

// ------------------------------------------------- QKV apply: K=32 per head
__global__ __launch_bounds__(256) void qkv_apply(
    const __hip_bfloat16* __restrict__ tq,
    const float* __restrict__ Vq, const float* __restrict__ bq,
    const float* __restrict__ Vk, const float* __restrict__ bk,
    const float* __restrict__ Vv, const float* __restrict__ bv,
    __hip_bfloat16* __restrict__ qkb, __hip_bfloat16* __restrict__ vt) {
  const int th = blockIdx.x;
  const int t = th / NH, h = th % NH;
  const int bm = blockIdx.y * 256;
  const float* V = (t == 0) ? Vq : (t == 1) ? Vk : Vv;   // [H][R][DH]
  const float* bb = (t == 0) ? bq : (t == 1) ? bk : bv;  // [H][DH]
  __shared__ __align__(16) __hip_bfloat16 Vl[NDH][NR];   // [dh][r]
  const int tid = threadIdx.x;
  const int lane = tid & 63, w = tid >> 6;
  const int g = lane >> 4, q = lane & 15;

  {
    int r = tid >> 3, dh0 = (tid & 7) * 8;
    const float* src = V + ((size_t)h * NR + r) * NDH + dh0;
#pragma unroll
    for (int j = 0; j < 8; j++) Vl[dh0 + j][r] = __float2bfloat16(src[j]);
  }
  __syncthreads();

  bf16x8 bfr[4];
  float bj[4];
#pragma unroll
  for (int j = 0; j < 4; j++) {
    bfr[j] = *(const bf16x8*)&Vl[j * 16 + q][g * 8];
    bj[j] = bb[h * NDH + j * 16 + q];
  }

  bf16x8 af[4];
#pragma unroll
  for (int i = 0; i < 4; i++) {
    int row = bm + w * 64 + i * 16 + q;
    af[i] = *(const bf16x8*)(tq + (size_t)row * NTQ + t * 384 + h * 32 + g * 8);
  }

  f32x4 acc[4][4];
#pragma unroll
  for (int i = 0; i < 4; i++)
#pragma unroll
    for (int j = 0; j < 4; j++) {
      acc[i][j] = f32x4{0.f, 0.f, 0.f, 0.f};
      acc[i][j] = __builtin_amdgcn_mfma_f32_16x16x32_bf16(af[i], bfr[j], acc[i][j], 0, 0, 0);
    }

  if (t < 2) {
#pragma unroll
    for (int i = 0; i < 4; i++)
#pragma unroll
      for (int j = 0; j < 4; j++) {
        int dh = j * 16 + q;
#pragma unroll
        for (int e = 0; e < 4; e++) {
          int row = bm + w * 64 + i * 16 + g * 4 + e;
          qkb[(size_t)row * NQK + t * NDM + h * NDH + dh] = __float2bfloat16(acc[i][j][e] + bj[j]);
        }
      }
  } else {
#pragma unroll
    for (int i = 0; i < 4; i++)
#pragma unroll
      for (int j = 0; j < 4; j++) {
        int dh = j * 16 + q;
        int row0 = bm + w * 64 + i * 16 + g * 4;
        int b = row0 >> 10, m0 = row0 & 1023;
        float bi = bj[j];
        ushort4 st = {f2bf(acc[i][j][0] + bi), f2bf(acc[i][j][1] + bi),
                      f2bf(acc[i][j][2] + bi), f2bf(acc[i][j][3] + bi)};
        *(ushort4*)&vt[(((size_t)b * NH + h) * NDH + dh) * NM + m0] = st;
      }
  }
}

// ------------------------------------------------------------- flash attention
// Single-buffered K/V (24KB LDS -> 6 blocks/CU; m114 inter-block overlap).
// No-max softmax, MFMA ones-frag row sums.
__global__ __launch_bounds__(256) void attn_kernel(const __hip_bfloat16* __restrict__ qk,
                                                   const __hip_bfloat16* __restrict__ vt,
                                                   const float* __restrict__ mask2,
                                                   __hip_bfloat16* __restrict__ attnb) {
  __shared__ __align__(16) char Kl[64 * 128];
  __shared__ __align__(16) char Vl[64 * 128];   // row = dh, col = n
  __shared__ __align__(16) char Pl[4][16 * 128];
  const int nblk = NB * NH * (NM / 64);
  const int blk = xcd_swizzle(blockIdx.x, nblk);
  const int qb = blk & 15;
  const int h = (blk >> 4) % NH;
  const int b = blk / (16 * NH);
  const int tid = threadIdx.x;
  const int lane = tid & 63, w = tid >> 6;
  const int g = lane >> 4, q = lane & 15;
  const size_t rowbase = (size_t)b * NM;
  const float S2 = 0.125f * 1.44269504088896f;

  const __hip_bfloat16* Kbase = qk + rowbase * NQK + NDM + h * 64;
  const __hip_bfloat16* Vbase = vt + ((size_t)(b * NH + h) * NDH) * NM;

  bf16x8 qf[2];
#pragma unroll
  for (int ks = 0; ks < 2; ks++)
    qf[ks] = *(const bf16x8*)(qk + (rowbase + qb * 64 + w * 16 + q) * NQK + h * 64 + g * 8 + ks * 32);

  bf16x8 onesf;
#pragma unroll
  for (int jj = 0; jj < 8; jj++) onesf[jj] = (__bf16)1.0f;

  const int l3 = lane >> 3;
  const int kc = (lane & 7) ^ l3;

  auto stage = [&](int t) {
    const int kv0 = t * 64;
#pragma unroll
    for (int c = 0; c < 2; c++) {
      int r8 = w * 16 + c * 8;
      int row = r8 + l3;
      const __hip_bfloat16* gk = Kbase + (size_t)(kv0 + row) * NQK + kc * 8;
      __builtin_amdgcn_global_load_lds(
          (const __attribute__((address_space(1))) void*)gk,
          (__attribute__((address_space(3))) void*)&Kl[r8 * 128], 16, 0, 0);
      const __hip_bfloat16* gv = Vbase + (size_t)row * NM + kv0 + kc * 8;
      __builtin_amdgcn_global_load_lds(
          (const __attribute__((address_space(1))) void*)gv,
          (__attribute__((address_space(3))) void*)&Vl[r8 * 128], 16, 0, 0);
    }
  };

  f32x4 oacc[4];
#pragma unroll
  for (int dt = 0; dt < 4; dt++) oacc[dt] = f32x4{0.f, 0.f, 0.f, 0.f};
  f32x4 lacc = f32x4{0.f, 0.f, 0.f, 0.f};

  for (int t = 0; t < NM / 64; t++) {
    stage(t);
    __syncthreads();   // waits vmcnt(0): K/V tile resident
    const int kv0 = t * 64;

    f32x4 sacc[4];
#pragma unroll
    for (int nt = 0; nt < 4; nt++) sacc[nt] = f32x4{0.f, 0.f, 0.f, 0.f};
    __builtin_amdgcn_s_setprio(1);
#pragma unroll
    for (int ks = 0; ks < 2; ks++) {
#pragma unroll
      for (int nt = 0; nt < 4; nt++) {
        int r = nt * 16 + q;
        bf16x8 kf = *(const bf16x8*)&Kl[r * 128 + ((ks * 64 + g * 16) ^ ((r & 7) << 4))];
        sacc[nt] = __builtin_amdgcn_mfma_f32_16x16x32_bf16(kf, qf[ks], sacc[nt], 0, 0, 0);
      }
    }
    __builtin_amdgcn_s_setprio(0);

#pragma unroll
    for (int nt = 0; nt < 4; nt++) {
      const float4 mk = *(const float4*)(mask2 + b * NM + kv0 + nt * 16 + g * 4);
      ushort4 pk;
      pk.x = f2bf(fexp2(fmaf(sacc[nt][0], S2, mk.x)));
      pk.y = f2bf(fexp2(fmaf(sacc[nt][1], S2, mk.y)));
      pk.z = f2bf(fexp2(fmaf(sacc[nt][2], S2, mk.z)));
      pk.w = f2bf(fexp2(fmaf(sacc[nt][3], S2, mk.w)));
      *(ushort4*)&Pl[w][q * 128 + ((nt * 32 + g * 8) ^ ((q & 7) << 4))] = pk;
    }

    __builtin_amdgcn_s_setprio(1);
#pragma unroll
    for (int ks = 0; ks < 2; ks++) {
      bf16x8 pf = *(const bf16x8*)&Pl[w][q * 128 + ((ks * 64 + g * 16) ^ ((q & 7) << 4))];
#pragma unroll
      for (int dt = 0; dt < 4; dt++) {
        int r = dt * 16 + q;
        bf16x8 vf = *(const bf16x8*)&Vl[r * 128 + ((ks * 64 + g * 16) ^ ((r & 7) << 4))];
        oacc[dt] = __builtin_amdgcn_mfma_f32_16x16x32_bf16(pf, vf, oacc[dt], 0, 0, 0);
      }
      lacc = __builtin_amdgcn_mfma_f32_16x16x32_bf16(pf, onesf, lacc, 0, 0, 0);
    }
    __builtin_amdgcn_s_setprio(0);
    __syncthreads();   // all waves done reading before next stage overwrites
  }

  float inv[4];
#pragma unroll
  for (int e = 0; e < 4; e++) inv[e] = 1.0f / lacc[e];
#pragma unroll
  for (int dt = 0; dt < 4; dt++)
#pragma unroll
    for (int e = 0; e < 4; e++) {
      int m = qb * 64 + w * 16 + g * 4 + e;
      int dh = dt * 16 + q;
      attnb[(rowbase + m) * NDM + h * 64 + dh] = __float2bfloat16(oacc[dt][e] * inv[e]);
    }
}

// ------------------------------------------------------------------- layernorm
// bf16 input; outf (f32) and/or outb (bf16)
__global__ __launch_bounds__(256) void ln_kernel(const __hip_bfloat16* __restrict__ in,
                                                 const float* __restrict__ gam,
                                                 const float* __restrict__ bet, float* __restrict__ outf,
                                                 __hip_bfloat16* __restrict__ outb) {
  const int row = blockIdx.x, tid = threadIdx.x;
  const __hip_bfloat16* p = in + (size_t)row * NDM;
  float v0 = __bfloat162float(p[tid]);
  float v1 = __bfloat162float(p[tid + 256]);
  float v2 = __bfloat162float(p[tid + 512]);
  float s = v0 + v1 + v2, s2 = v0 * v0 + v1 * v1 + v2 * v2;
#pragma unroll
  for (int d = 1; d < 64; d <<= 1) {
    s += __shfl_xor(s, d);
    s2 += __shfl_xor(s2, d);
  }
  __shared__ float red[8];
  int w = tid >> 6;
  if ((tid & 63) == 0) { red[w] = s; red[4 + w] = s2; }
  __syncthreads();
  s = red[0] + red[1] + red[2] + red[3];
  s2 = red[4] + red[5] + red[6] + red[7];
  float mu = s * (1.0f / NDM);
  float var = fmaxf(s2 * (1.0f / NDM) - mu * mu, 0.0f);
  float rr = rsqrtf(var + 1e-12f);
  float o0 = (v0 - mu) * rr * gam[tid] + bet[tid];
  float o1 = (v1 - mu) * rr * gam[tid + 256] + bet[tid + 256];
  float o2 = (v2 - mu) * rr * gam[tid + 512] + bet[tid + 512];
  if (outf) {
    float* po = outf + (size_t)row * NDM;
    po[tid] = o0;
    po[tid + 256] = o1;
    po[tid + 512] = o2;
  }
  if (outb) {
    __hip_bfloat16* pb = outb + (size_t)row * NDM;
    pb[tid] = __float2bfloat16(o0);
    pb[tid + 256] = __float2bfloat16(o1);
    pb[tid + 512] = __float2bfloat16(o2);
  }
}

// ------------------------------------------------------------------- launcher
extern "C" void kernel_launch(void* const* d_in, const int* in_sizes, int n_in,
                              void* d_out, int out_size, void* d_ws, size_t ws_size,
                              hipStream_t stream) {
  const float* x = (const float*)d_in[0];
  const float* mask = (const float*)d_in[1];
  const float* Pq = (const float*)d_in[2];
  const float* Vq = (const float*)d_in[3];
  const float* bq = (const float*)d_in[4];
  const float* Pk = (const float*)d_in[5];
  const float* Vk = (const float*)d_in[6];
  const float* bk = (const float*)d_in[7];
  const float* Pv = (const float*)d_in[8];
  const float* Vv = (const float*)d_in[9];
  const float* bv = (const float*)d_in[10];
  const float* Uo = (const float*)d_in[11];
  const float* Vo = (const float*)d_in[12];
  const float* bo = (const float*)d_in[13];
  const float* U1 = (const float*)d_in[14];
  const float* V1 = (const float*)d_in[15];
  const float* b1 = (const float*)d_in[16];
  const float* U2 = (const float*)d_in[17];
  const float* V2 = (const float*)d_in[18];
  const float* b2 = (const float*)d_in[19];
  const float* ln1g = (const float*)d_in[20];
  const float* ln1b = (const float*)d_in[21];
  const float* ln2g = (const float*)d_in[22];
  const float* ln2b = (const float*)d_in[23];
  float* out = (float*)d_out;
  char* ws = (char*)d_ws;

  size_t off = 0;
  auto alloc = [&](size_t bytes) { size_t o = off; off += (bytes + 255) & ~(size_t)255; return o; };
  const size_t o_xb    = alloc((size_t)ROWS * NDM * 2);
  const size_t o_woT   = alloc((size_t)NDM * NDM * 2);
  const size_t o_uoB   = alloc((size_t)NDM * NRWO * 2);
  const size_t o_voT   = alloc((size_t)NDM * NRWO * 2);
  const size_t o_u1T   = alloc((size_t)NRFF * NDM * 2);
  const size_t o_v1T   = alloc((size_t)NDFF * NRFF * 2);
  const size_t o_u2T   = alloc((size_t)NRFF * NDFF * 2);
  const size_t o_v2T   = alloc((size_t)NDM * NRFF * 2);
  const size_t o_ptT   = alloc((size_t)NTQ * NDM * 2);
  const size_t o_mask2 = alloc((size_t)NB * NM * 4);
  const size_t o_tq    = alloc((size_t)ROWS * NTQ * 2);
  const size_t o_qk    = alloc((size_t)ROWS * NQK * 2);
  const size_t o_vt    = alloc((size_t)NB * NH * NDH * NM * 2);
  const size_t o_attnb = alloc((size_t)ROWS * NDM * 2);
  const size_t o_tmpb  = alloc((size_t)ROWS * NDM * 2);
  const size_t o_x1b   = alloc((size_t)ROWS * NDM * 2);
  const size_t o_mid   = alloc((size_t)ROWS * NRFF * 2);
  const size_t o_mid2  = alloc((size_t)ROWS * NRFF * 2);
  const size_t o_hdn   = o_qk;  // hdn [8192][3072] bf16 = 50.3MB over qk+vt+attnb

  __hip_bfloat16* xb    = (__hip_bfloat16*)(ws + o_xb);
  __hip_bfloat16* woT   = (__hip_bfloat16*)(ws + o_woT);
  __hip_bfloat16* uoB   = (__hip_bfloat16*)(ws + o_uoB);
  __hip_bfloat16* voT   = (__hip_bfloat16*)(ws + o_voT);
  __hip_bfloat16* u1T   = (__hip_bfloat16*)(ws + o_u1T);
  __hip_bfloat16* v1T   = (__hip_bfloat16*)(ws + o_v1T);
  __hip_bfloat16* u2T   = (__hip_bfloat16*)(ws + o_u2T);
  __hip_bfloat16* v2T   = (__hip_bfloat16*)(ws + o_v2T);
  __hip_bfloat16* ptT   = (__hip_bfloat16*)(ws + o_ptT);
  float*          mask2 = (float*)(ws + o_mask2);
  __hip_bfloat16* tq    = (__hip_bfloat16*)(ws + o_tq);
  __hip_bfloat16* qkb   = (__hip_bfloat16*)(ws + o_qk);
  __hip_bfloat16* vt    = (__hip_bfloat16*)(ws + o_vt);
  __hip_bfloat16* attnb = (__hip_bfloat16*)(ws + o_attnb);
  __hip_bfloat16* tmpb  = (__hip_bfloat16*)(ws + o_tmpb);
  __hip_bfloat16* x1b   = (__hip_bfloat16*)(ws + o_x1b);
  __hip_bfloat16* mid   = (__hip_bfloat16*)(ws + o_mid);
  __hip_bfloat16* mid2  = (__hip_bfloat16*)(ws + o_mid2);
  __hip_bfloat16* hdn   = (__hip_bfloat16*)(ws + o_hdn);

  // --- all preps in one launch
  prep_all<<<2248, 256, 0, stream>>>(x, Uo, mask, Vo, U1, V1, U2, V2, Pq, Pk, Pv,
                                     xb, uoB, mask2, voT, u1T, v1T, u2T, v2T, ptT);

  // --- WoT[n][k] = sum_r voT[n][r] * Uo[k][r]
  gemm_bt<0, 64><<<dim3(NDM / 64, NDM / 128), 256, 0, stream>>>(
      voT, uoB, NDM, NDM, NRWO, nullptr, nullptr, woT);

  // --- tq = xb @ ptT^T   [8192][1152]
  gemm_bt<0, 128><<<dim3(NTQ / 128, ROWS / 128), 256, 0, stream>>>(
      xb, ptT, ROWS, NTQ, NDM, nullptr, nullptr, tq);

  // --- apply V + bias: Q/K -> qkb, V -> vt
  qkv_apply<<<dim3(36, ROWS / 256), 256, 0, stream>>>(tq, Vq, bq, Vk, bk, Vv, bv, qkb, vt);

  // --- attention
  attn_kernel<<<NB * NH * (NM / 64), 256, 0, stream>>>(qkb, vt, mask2, attnb);

  // --- Wo proj + bias + residual(xb) -> tmpb (bf16); LN1 -> x1b
  gemm_bt<5, 64><<<dim3(NDM / 64, ROWS / 128), 256, 0, stream>>>(
      attnb, woT, ROWS, NDM, NDM, bo, xb, tmpb);
  ln_kernel<<<ROWS, 256, 0, stream>>>(tmpb, ln1g, ln1b, nullptr, x1b);

  // --- FFN
  gemm_bt<0, 64><<<dim3(NRFF / 64, ROWS / 128), 256, 0, stream>>>(
      x1b, u1T, ROWS, NRFF, NDM, nullptr, nullptr, mid);
  gemm_bt<2, 128><<<dim3(NDFF / 128, ROWS / 128), 256, 0, stream>>>(
      mid, v1T, ROWS, NDFF, NRFF, b1, nullptr, hdn);
  gemm_bt<0, 64><<<dim3(NRFF / 64, ROWS / 128), 256, 0, stream>>>(
      hdn, u2T, ROWS, NRFF, NDFF, nullptr, nullptr, mid2);
  gemm_bt<5, 64><<<dim3(NDM / 64, ROWS / 128), 256, 0, stream>>>(
      mid2, v2T, ROWS, NDM, NRFF, b2, x1b, tmpb);

  // --- LN2 -> out (f32)
  ln_kernel<<<ROWS, 256, 0, stream>>>(tmpb, ln2g, ln2b, out, nullptr);

  (void)in_sizes; (void)n_in; (void)out_size; (void)ws_size;
}